// Round 1
// baseline (1513.091 us; speedup 1.0000x reference)
//
#include <hip/hip_runtime.h>
#include <hip/hip_bf16.h>
#include <cmath>

// ---------------------------------------------------------------------------
// Mamba block, f32 baseline.
//   B=2, L=2048, D_MODEL=512, D_INNER=1024, D_STATE=16, D_CONV=4, EPS=1e-8
// Workspace layout (floats):
//   xr   : (B,L,2048)  = 8,388,608   x_inner cols[0:1024), res cols[1024:2048)
//                        (x_inner half later overwritten with y_act)
//   xc   : (B,L,1024)  = 4,194,304
//   scal : (B,L,48)    =   196,608   [0:16)=B_sel, [16:32)=C_sel, [32:48)=ab->r
//   S    : (B,16,16,1024) = 524,288  per-chunk local end states
//   Hin  : (B,16,16,1024) = 524,288  per-chunk corrected init states
//   RP   : (B,16,16)   =       512   per-chunk rate products
// total ~55.3 MB
// ---------------------------------------------------------------------------

#define L_SEQ 2048
#define NBATCH 2
#define DI 1024
#define NC 16
#define LC 128
#define EPS_F 1e-8f

__device__ __forceinline__ float silu_f(float v) {
    return v / (1.f + __expf(-v));
}

// ---------------- generic 64x64 tiled f32 GEMM with bias -------------------
// C[M,N] = A[M,K] @ B[K,N] + bias[N].  M % 64 == 0, K % 16 == 0.
// NG: guard columns against Nvalid (used for the N=33 GEMM).
template<bool NG>
__global__ __launch_bounds__(256) void gemm_bias(
    const float* __restrict__ A, const float* __restrict__ B,
    const float* __restrict__ bias, float* __restrict__ C,
    int K, int lda, int ldb, int ldc, int Nvalid)
{
    __shared__ float As[16][68];   // [k][m], 68 stride: 16B-aligned rows, 2-way banks
    __shared__ float Bs[16][68];   // [k][n]
    const int tid = threadIdx.x;
    const int tx = tid & 15, ty = tid >> 4;
    const int bm = blockIdx.y * 64, bn = blockIdx.x * 64;
    const int am = tid >> 2, ak = (tid & 3) * 4;
    const int bk = tid >> 4, bn4 = (tid & 15) * 4;
    float acc[4][4] = {};
    const float* Ap = A + (long)(bm + am) * lda + ak;

    for (int k0 = 0; k0 < K; k0 += 16) {
        float4 av = *reinterpret_cast<const float4*>(Ap + k0);
        As[ak + 0][am] = av.x; As[ak + 1][am] = av.y;
        As[ak + 2][am] = av.z; As[ak + 3][am] = av.w;
        if (NG) {
            #pragma unroll
            for (int j = 0; j < 4; ++j) {
                int n = bn + bn4 + j;
                Bs[bk][bn4 + j] = (n < Nvalid) ? B[(long)(k0 + bk) * ldb + n] : 0.f;
            }
        } else {
            float4 bv = *reinterpret_cast<const float4*>(B + (long)(k0 + bk) * ldb + bn + bn4);
            Bs[bk][bn4 + 0] = bv.x; Bs[bk][bn4 + 1] = bv.y;
            Bs[bk][bn4 + 2] = bv.z; Bs[bk][bn4 + 3] = bv.w;
        }
        __syncthreads();
        #pragma unroll
        for (int k = 0; k < 16; ++k) {
            float a[4], b[4];
            *reinterpret_cast<float4*>(a) = *reinterpret_cast<const float4*>(&As[k][ty * 4]);
            *reinterpret_cast<float4*>(b) = *reinterpret_cast<const float4*>(&Bs[k][tx * 4]);
            #pragma unroll
            for (int i = 0; i < 4; ++i)
                #pragma unroll
                for (int j = 0; j < 4; ++j)
                    acc[i][j] = fmaf(a[i], b[j], acc[i][j]);
        }
        __syncthreads();
    }

    #pragma unroll
    for (int i = 0; i < 4; ++i) {
        int gm = bm + ty * 4 + i;
        if (NG) {
            #pragma unroll
            for (int j = 0; j < 4; ++j) {
                int gn = bn + tx * 4 + j;
                if (gn < Nvalid) C[(long)gm * ldc + gn] = acc[i][j] + bias[gn];
            }
        } else {
            int gn = bn + tx * 4;
            float4 o;
            o.x = acc[i][0] + bias[gn + 0];
            o.y = acc[i][1] + bias[gn + 1];
            o.z = acc[i][2] + bias[gn + 2];
            o.w = acc[i][3] + bias[gn + 3];
            *reinterpret_cast<float4*>(C + (long)gm * ldc + gn) = o;
        }
    }
}

// ---------------- depthwise causal conv(4) + SiLU --------------------------
__global__ __launch_bounds__(256) void conv_silu(
    const float* __restrict__ xr, const float* __restrict__ cw,
    const float* __restrict__ cb, float* __restrict__ xc)
{
    int idx = blockIdx.x * 256 + threadIdx.x;     // B*L*DI threads
    int d = idx & (DI - 1);
    int l = (idx >> 10) & (L_SEQ - 1);
    // b = idx >> 21 folded into base below
    float4 w = *reinterpret_cast<const float4*>(cw + d * 4);
    float acc = cb[d];
    long base = ((long)(idx >> 10)) * 2048 + d;   // (b*L + l)*2048 + d
    if (l >= 3) acc = fmaf(xr[base - 3 * 2048], w.x, acc);
    if (l >= 2) acc = fmaf(xr[base - 2 * 2048], w.y, acc);
    if (l >= 1) acc = fmaf(xr[base - 1 * 2048], w.z, acc);
    acc = fmaf(xr[base], w.w, acc);
    xc[idx] = silu_f(acc);
}

// ---------------- sequential rates: ab -> r, per-chunk products ------------
// scal[b][l][32] holds raw dt logit on entry; cols [32:48) get r on exit.
__global__ void rates_seq(float* __restrict__ scal, const float* __restrict__ A_log,
                          float* __restrict__ RP)
{
    int b = blockIdx.x;
    int lane = threadIdx.x;           // one wave; lanes 16..63 shadow lanes 0..15
    int s = lane & 15;
    float Aneg = -__expf(A_log[s]);
    float cp = 1.f, Pprev = 1.f, rp = 1.f;
    float* base = scal + (long)b * L_SEQ * 48;
    for (int l = 0; l < L_SEQ; ++l) {
        float draw = base[l * 48 + 32];
        float dt = (draw > 20.f) ? draw : log1pf(__expf(draw));
        float ab = __expf(dt * Aneg);
        cp = cp * ab;
        float P = fmaxf(cp, EPS_F);
        float r = P / Pprev;
        Pprev = P;
        rp *= r;
        if (lane < 16) base[l * 48 + 32 + s] = r;   // write after uniform read of col 32
        if ((l & (LC - 1)) == (LC - 1)) {
            if (lane < 16) RP[(b * NC + (l >> 7)) * 16 + s] = rp;
            rp = 1.f;
        }
    }
}

// ---------------- phase A: per-chunk local end states ----------------------
__global__ __launch_bounds__(128) void scan_states(
    const float* __restrict__ scal, const float* __restrict__ xc,
    float* __restrict__ S)
{
    int b = blockIdx.z, c = blockIdx.y;
    int d = blockIdx.x * 128 + threadIdx.x;
    __shared__ float sc[LC * 48];
    const float4* src = reinterpret_cast<const float4*>(scal + ((long)(b * L_SEQ) + c * LC) * 48);
    float4* dst = reinterpret_cast<float4*>(sc);
    for (int i = threadIdx.x; i < LC * 48 / 4; i += 128) dst[i] = src[i];
    __syncthreads();
    float h[16];
    #pragma unroll
    for (int s = 0; s < 16; ++s) h[s] = 0.f;
    const float* xcp = xc + ((long)(b * L_SEQ) + c * LC) * 1024 + d;
    for (int ll = 0; ll < LC; ++ll) {
        float xcv = xcp[(long)ll * 1024];
        const float* e = sc + ll * 48;
        #pragma unroll
        for (int s = 0; s < 16; ++s) h[s] = fmaf(e[32 + s], h[s], e[s] * xcv);
    }
    float* Sp = S + ((long)(b * NC + c) * 16) * 1024 + d;
    #pragma unroll
    for (int s = 0; s < 16; ++s) Sp[(long)s * 1024] = h[s];
}

// ---------------- stitch: chunk-boundary states ----------------------------
__global__ __launch_bounds__(256) void stitch(
    const float* __restrict__ S, const float* __restrict__ RP,
    float* __restrict__ Hin)
{
    int b = blockIdx.y;
    int d = blockIdx.x * 256 + threadIdx.x;
    float H[16];
    #pragma unroll
    for (int s = 0; s < 16; ++s) H[s] = 0.f;
    for (int c = 0; c < NC; ++c) {
        long off = ((long)(b * NC + c) * 16) * 1024 + d;
        #pragma unroll
        for (int s = 0; s < 16; ++s) Hin[off + (long)s * 1024] = H[s];
        #pragma unroll
        for (int s = 0; s < 16; ++s)
            H[s] = fmaf(RP[(b * NC + c) * 16 + s], H[s], S[off + (long)s * 1024]);
    }
}

// ---------------- phase B: full scan + y + gating --------------------------
// writes y_act into xr cols [0:1024) (x_inner no longer needed)
__global__ __launch_bounds__(128) void scan_out(
    const float* __restrict__ scal, const float* __restrict__ xc,
    const float* __restrict__ Hin, const float* __restrict__ Dw,
    float* __restrict__ xr)
{
    int b = blockIdx.z, c = blockIdx.y;
    int d = blockIdx.x * 128 + threadIdx.x;
    __shared__ float sc[LC * 48];
    const float4* src = reinterpret_cast<const float4*>(scal + ((long)(b * L_SEQ) + c * LC) * 48);
    float4* dst = reinterpret_cast<float4*>(sc);
    for (int i = threadIdx.x; i < LC * 48 / 4; i += 128) dst[i] = src[i];
    __syncthreads();
    float h[16];
    long hoff = ((long)(b * NC + c) * 16) * 1024 + d;
    #pragma unroll
    for (int s = 0; s < 16; ++s) h[s] = Hin[hoff + (long)s * 1024];
    float Dd = Dw[d];
    for (int ll = 0; ll < LC; ++ll) {
        long row = (long)(b * L_SEQ) + c * LC + ll;
        float xcv = xc[row * 1024 + d];
        float resv = xr[row * 2048 + 1024 + d];
        const float* e = sc + ll * 48;
        float y = 0.f;
        #pragma unroll
        for (int s = 0; s < 16; ++s) {
            h[s] = fmaf(e[32 + s], h[s], e[s] * xcv);
            y = fmaf(e[16 + s], h[s], y);
        }
        y = fmaf(Dd, xcv, y);
        xr[row * 2048 + d] = y * silu_f(resv);
    }
}

// ---------------------------------------------------------------------------
extern "C" void kernel_launch(void* const* d_in, const int* in_sizes, int n_in,
                              void* d_out, int out_size, void* d_ws, size_t ws_size,
                              hipStream_t stream)
{
    const float* x      = (const float*)d_in[0];
    const float* W_in   = (const float*)d_in[1];
    const float* b_in   = (const float*)d_in[2];
    const float* conv_w = (const float*)d_in[3];
    const float* conv_b = (const float*)d_in[4];
    const float* W_x    = (const float*)d_in[5];
    const float* b_x    = (const float*)d_in[6];
    const float* A_log  = (const float*)d_in[7];
    const float* Dw     = (const float*)d_in[8];
    const float* W_out  = (const float*)d_in[9];
    const float* b_out  = (const float*)d_in[10];
    float* out = (float*)d_out;

    float* ws   = (float*)d_ws;
    float* xr   = ws;                       // 8,388,608
    float* xc   = xr + 8388608;             // 4,194,304
    float* scal = xc + 4194304;             //   196,608
    float* S    = scal + 196608;            //   524,288
    float* Hin  = S + 524288;               //   524,288
    float* RP   = Hin + 524288;             //       512

    // 1. xr = x @ W_in + b_in        (4096 x 2048, K=512)
    gemm_bias<false><<<dim3(2048 / 64, 4096 / 64), 256, 0, stream>>>(
        x, W_in, b_in, xr, 512, 512, 2048, 2048, 2048);

    // 2. xc = silu(depthwise_conv(x_inner))
    conv_silu<<<(NBATCH * L_SEQ * DI) / 256, 256, 0, stream>>>(xr, conv_w, conv_b, xc);

    // 3. scal[:, :, 0:33] = xc @ W_x + b_x   (4096 x 33, K=1024, ldc=48)
    gemm_bias<true><<<dim3(1, 4096 / 64), 256, 0, stream>>>(
        xc, W_x, b_x, scal, 1024, 1024, 33, 48, 33);

    // 4. sequential cumprod -> per-step rates r, per-chunk products RP
    rates_seq<<<NBATCH, 64, 0, stream>>>(scal, A_log, RP);

    // 5. phase A: local chunk scans -> S
    scan_states<<<dim3(DI / 128, NC, NBATCH), 128, 0, stream>>>(scal, xc, S);

    // 6. stitch chunk boundary states -> Hin
    stitch<<<dim3(DI / 256, NBATCH), 256, 0, stream>>>(S, RP, Hin);

    // 7. phase B: full scan, y = C.h + D*xc, gate with silu(res) -> xr[:, :, 0:1024)
    scan_out<<<dim3(DI / 128, NC, NBATCH), 128, 0, stream>>>(scal, xc, Hin, Dw, xr);

    // 8. out = y_act @ W_out + b_out   (4096 x 512, K=1024, lda=2048)
    gemm_bias<false><<<dim3(512 / 64, 4096 / 64), 256, 0, stream>>>(
        xr, W_out, b_out, out, 1024, 2048, 512, 512, 512);
}

// Round 2
// 406.619 us; speedup vs baseline: 3.7211x; 3.7211x over previous
//
#include <hip/hip_runtime.h>
#include <hip/hip_bf16.h>
#include <cmath>

// ---------------------------------------------------------------------------
// Mamba block, f32 baseline + parallel log-space rates.
//   B=2, L=2048, D_MODEL=512, D_INNER=1024, D_STATE=16, D_CONV=4, EPS=1e-8
// Workspace layout (floats):
//   xr   : (B,L,2048)  = 8,388,608   x_inner cols[0:1024), res cols[1024:2048)
//   xc   : (B,L,1024)  = 4,194,304
//   scal : (B,L,48)    =   196,608   [0:16)=B_sel, [16:32)=C_sel, [32:48)=dt->r
//   S    : (B,16,16,1024) = 524,288  per-chunk local end states
//   Hin  : (B,16,16,1024) = 524,288  per-chunk corrected init states
//   RP   : (B,16,16)   =       512   per-chunk rate products
// ---------------------------------------------------------------------------

#define L_SEQ 2048
#define NBATCH 2
#define DI 1024
#define NC 16
#define LC 128
#define EPS_F 1e-8f
#define LOG_EPS -18.420680744f

__device__ __forceinline__ float silu_f(float v) {
    return v / (1.f + __expf(-v));
}

// ---------------- generic 64x64 tiled f32 GEMM with bias -------------------
template<bool NG>
__global__ __launch_bounds__(256) void gemm_bias(
    const float* __restrict__ A, const float* __restrict__ B,
    const float* __restrict__ bias, float* __restrict__ C,
    int K, int lda, int ldb, int ldc, int Nvalid)
{
    __shared__ float As[16][68];
    __shared__ float Bs[16][68];
    const int tid = threadIdx.x;
    const int tx = tid & 15, ty = tid >> 4;
    const int bm = blockIdx.y * 64, bn = blockIdx.x * 64;
    const int am = tid >> 2, ak = (tid & 3) * 4;
    const int bk = tid >> 4, bn4 = (tid & 15) * 4;
    float acc[4][4] = {};
    const float* Ap = A + (long)(bm + am) * lda + ak;

    for (int k0 = 0; k0 < K; k0 += 16) {
        float4 av = *reinterpret_cast<const float4*>(Ap + k0);
        As[ak + 0][am] = av.x; As[ak + 1][am] = av.y;
        As[ak + 2][am] = av.z; As[ak + 3][am] = av.w;
        if (NG) {
            #pragma unroll
            for (int j = 0; j < 4; ++j) {
                int n = bn + bn4 + j;
                Bs[bk][bn4 + j] = (n < Nvalid) ? B[(long)(k0 + bk) * ldb + n] : 0.f;
            }
        } else {
            float4 bv = *reinterpret_cast<const float4*>(B + (long)(k0 + bk) * ldb + bn + bn4);
            Bs[bk][bn4 + 0] = bv.x; Bs[bk][bn4 + 1] = bv.y;
            Bs[bk][bn4 + 2] = bv.z; Bs[bk][bn4 + 3] = bv.w;
        }
        __syncthreads();
        #pragma unroll
        for (int k = 0; k < 16; ++k) {
            float a[4], b[4];
            *reinterpret_cast<float4*>(a) = *reinterpret_cast<const float4*>(&As[k][ty * 4]);
            *reinterpret_cast<float4*>(b) = *reinterpret_cast<const float4*>(&Bs[k][tx * 4]);
            #pragma unroll
            for (int i = 0; i < 4; ++i)
                #pragma unroll
                for (int j = 0; j < 4; ++j)
                    acc[i][j] = fmaf(a[i], b[j], acc[i][j]);
        }
        __syncthreads();
    }

    #pragma unroll
    for (int i = 0; i < 4; ++i) {
        int gm = bm + ty * 4 + i;
        if (NG) {
            #pragma unroll
            for (int j = 0; j < 4; ++j) {
                int gn = bn + tx * 4 + j;
                if (gn < Nvalid) C[(long)gm * ldc + gn] = acc[i][j] + bias[gn];
            }
        } else {
            int gn = bn + tx * 4;
            float4 o;
            o.x = acc[i][0] + bias[gn + 0];
            o.y = acc[i][1] + bias[gn + 1];
            o.z = acc[i][2] + bias[gn + 2];
            o.w = acc[i][3] + bias[gn + 3];
            *reinterpret_cast<float4*>(C + (long)gm * ldc + gn) = o;
        }
    }
}

// ---------------- depthwise causal conv(4) + SiLU --------------------------
__global__ __launch_bounds__(256) void conv_silu(
    const float* __restrict__ xr, const float* __restrict__ cw,
    const float* __restrict__ cb, float* __restrict__ xc)
{
    int idx = blockIdx.x * 256 + threadIdx.x;
    int d = idx & (DI - 1);
    int l = (idx >> 10) & (L_SEQ - 1);
    float4 w = *reinterpret_cast<const float4*>(cw + d * 4);
    float acc = cb[d];
    long base = ((long)(idx >> 10)) * 2048 + d;
    if (l >= 3) acc = fmaf(xr[base - 3 * 2048], w.x, acc);
    if (l >= 2) acc = fmaf(xr[base - 2 * 2048], w.y, acc);
    if (l >= 1) acc = fmaf(xr[base - 1 * 2048], w.z, acc);
    acc = fmaf(xr[base], w.w, acc);
    xc[idx] = silu_f(acc);
}

// ---------------- parallel rates via log-space scan ------------------------
// One block of 256 per batch. scal col 32 holds raw dt logit on entry;
// cols [32:48) get per-step rates r on exit. RP gets per-chunk products.
//
// cumprod(A_bar)_l = exp(Aneg_s * cdt_l), cdt = cumsum(softplus(raw)).
// Unclamped (Aneg*cdt >= ln EPS):  r = exp(Aneg*dt_l)   (exact, no scan error)
// Transition step:                 r = EPS / P_{l-1}
// Fully clamped:                   r = 1
__global__ __launch_bounds__(256) void rates_par(
    float* __restrict__ scal, const float* __restrict__ A_log,
    float* __restrict__ RP)
{
    int b = blockIdx.x;
    int t = threadIdx.x;
    __shared__ float cdt[L_SEQ];
    __shared__ float wsum[4];
    __shared__ float An[16];
    if (t < 16) An[t] = -__expf(A_log[t]);
    float* base = scal + (long)b * L_SEQ * 48;

    // 1. softplus + per-thread serial prefix (8 contiguous l per thread)
    float dt[8];
    float run = 0.f;
    const int l0 = t * 8;
    #pragma unroll
    for (int i = 0; i < 8; ++i) {
        float raw = base[(l0 + i) * 48 + 32];
        float d = (raw > 20.f) ? raw : log1pf(__expf(raw));
        dt[i] = d;
        run += d;
        cdt[l0 + i] = run;
    }

    // 2. wave inclusive scan of per-thread totals, then cross-wave combine
    float x = run;
    int lane = t & 63;
    #pragma unroll
    for (int d = 1; d < 64; d <<= 1) {
        float v = __shfl_up(x, d, 64);
        if (lane >= d) x += v;
    }
    int w = t >> 6;
    if (lane == 63) wsum[w] = x;
    __syncthreads();
    float woff = 0.f;
    for (int i = 0; i < w; ++i) woff += wsum[i];
    float toff = woff + x - run;          // exclusive prefix for this thread
    #pragma unroll
    for (int i = 0; i < 8; ++i) cdt[l0 + i] += toff;
    __syncthreads();

    // 3. per-step rates
    float cprev = (l0 == 0) ? 0.f : cdt[l0 - 1];
    #pragma unroll
    for (int i = 0; i < 8; ++i) {
        int l = l0 + i;
        float cl = cdt[l];
        float rv[16];
        #pragma unroll
        for (int s = 0; s < 16; ++s) {
            float A = An[s];
            float r;
            if (A * cl >= LOG_EPS) {
                r = __expf(A * dt[i]);                 // unclamped: exact A_bar
            } else {
                float lp = A * cprev;
                r = (lp >= LOG_EPS) ? EPS_F / __expf(lp) : 1.f;
            }
            rv[s] = r;
        }
        float4* dst = reinterpret_cast<float4*>(base + l * 48 + 32);
        dst[0] = *reinterpret_cast<float4*>(&rv[0]);
        dst[1] = *reinterpret_cast<float4*>(&rv[4]);
        dst[2] = *reinterpret_cast<float4*>(&rv[8]);
        dst[3] = *reinterpret_cast<float4*>(&rv[12]);
        cprev = cl;
    }

    // 4. per-chunk rate products RP[c][s] = P(end c) / P(end c-1)
    if ((t & 15) == 15) {
        int c = t >> 4;                    // 0..15
        float ce = cdt[c * LC + LC - 1];
        float cp = (c == 0) ? 0.f : cdt[c * LC - 1];
        for (int s = 0; s < 16; ++s) {
            float A = An[s];
            float pe = fmaxf(__expf(A * ce), EPS_F);
            float pp = fmaxf(__expf(A * cp), EPS_F);
            RP[(b * NC + c) * 16 + s] = pe / pp;
        }
    }
}

// ---------------- phase A: per-chunk local end states ----------------------
__global__ __launch_bounds__(128) void scan_states(
    const float* __restrict__ scal, const float* __restrict__ xc,
    float* __restrict__ S)
{
    int b = blockIdx.z, c = blockIdx.y;
    int d = blockIdx.x * 128 + threadIdx.x;
    __shared__ float sc[LC * 48];
    const float4* src = reinterpret_cast<const float4*>(scal + ((long)(b * L_SEQ) + c * LC) * 48);
    float4* dst = reinterpret_cast<float4*>(sc);
    for (int i = threadIdx.x; i < LC * 48 / 4; i += 128) dst[i] = src[i];
    __syncthreads();
    float h[16];
    #pragma unroll
    for (int s = 0; s < 16; ++s) h[s] = 0.f;
    const float* xcp = xc + ((long)(b * L_SEQ) + c * LC) * 1024 + d;
    for (int ll = 0; ll < LC; ++ll) {
        float xcv = xcp[(long)ll * 1024];
        const float* e = sc + ll * 48;
        #pragma unroll
        for (int s = 0; s < 16; ++s) h[s] = fmaf(e[32 + s], h[s], e[s] * xcv);
    }
    float* Sp = S + ((long)(b * NC + c) * 16) * 1024 + d;
    #pragma unroll
    for (int s = 0; s < 16; ++s) Sp[(long)s * 1024] = h[s];
}

// ---------------- stitch: chunk-boundary states ----------------------------
__global__ __launch_bounds__(256) void stitch(
    const float* __restrict__ S, const float* __restrict__ RP,
    float* __restrict__ Hin)
{
    int b = blockIdx.y;
    int d = blockIdx.x * 256 + threadIdx.x;
    float H[16];
    #pragma unroll
    for (int s = 0; s < 16; ++s) H[s] = 0.f;
    for (int c = 0; c < NC; ++c) {
        long off = ((long)(b * NC + c) * 16) * 1024 + d;
        #pragma unroll
        for (int s = 0; s < 16; ++s) Hin[off + (long)s * 1024] = H[s];
        #pragma unroll
        for (int s = 0; s < 16; ++s)
            H[s] = fmaf(RP[(b * NC + c) * 16 + s], H[s], S[off + (long)s * 1024]);
    }
}

// ---------------- phase B: full scan + y + gating --------------------------
__global__ __launch_bounds__(128) void scan_out(
    const float* __restrict__ scal, const float* __restrict__ xc,
    const float* __restrict__ Hin, const float* __restrict__ Dw,
    float* __restrict__ xr)
{
    int b = blockIdx.z, c = blockIdx.y;
    int d = blockIdx.x * 128 + threadIdx.x;
    __shared__ float sc[LC * 48];
    const float4* src = reinterpret_cast<const float4*>(scal + ((long)(b * L_SEQ) + c * LC) * 48);
    float4* dst = reinterpret_cast<float4*>(sc);
    for (int i = threadIdx.x; i < LC * 48 / 4; i += 128) dst[i] = src[i];
    __syncthreads();
    float h[16];
    long hoff = ((long)(b * NC + c) * 16) * 1024 + d;
    #pragma unroll
    for (int s = 0; s < 16; ++s) h[s] = Hin[hoff + (long)s * 1024];
    float Dd = Dw[d];
    for (int ll = 0; ll < LC; ++ll) {
        long row = (long)(b * L_SEQ) + c * LC + ll;
        float xcv = xc[row * 1024 + d];
        float resv = xr[row * 2048 + 1024 + d];
        const float* e = sc + ll * 48;
        float y = 0.f;
        #pragma unroll
        for (int s = 0; s < 16; ++s) {
            h[s] = fmaf(e[32 + s], h[s], e[s] * xcv);
            y = fmaf(e[16 + s], h[s], y);
        }
        y = fmaf(Dd, xcv, y);
        xr[row * 2048 + d] = y * silu_f(resv);
    }
}

// ---------------------------------------------------------------------------
extern "C" void kernel_launch(void* const* d_in, const int* in_sizes, int n_in,
                              void* d_out, int out_size, void* d_ws, size_t ws_size,
                              hipStream_t stream)
{
    const float* x      = (const float*)d_in[0];
    const float* W_in   = (const float*)d_in[1];
    const float* b_in   = (const float*)d_in[2];
    const float* conv_w = (const float*)d_in[3];
    const float* conv_b = (const float*)d_in[4];
    const float* W_x    = (const float*)d_in[5];
    const float* b_x    = (const float*)d_in[6];
    const float* A_log  = (const float*)d_in[7];
    const float* Dw     = (const float*)d_in[8];
    const float* W_out  = (const float*)d_in[9];
    const float* b_out  = (const float*)d_in[10];
    float* out = (float*)d_out;

    float* ws   = (float*)d_ws;
    float* xr   = ws;
    float* xc   = xr + 8388608;
    float* scal = xc + 4194304;
    float* S    = scal + 196608;
    float* Hin  = S + 524288;
    float* RP   = Hin + 524288;

    // 1. xr = x @ W_in + b_in        (4096 x 2048, K=512)
    gemm_bias<false><<<dim3(2048 / 64, 4096 / 64), 256, 0, stream>>>(
        x, W_in, b_in, xr, 512, 512, 2048, 2048, 2048);

    // 2. xc = silu(depthwise_conv(x_inner))
    conv_silu<<<(NBATCH * L_SEQ * DI) / 256, 256, 0, stream>>>(xr, conv_w, conv_b, xc);

    // 3. scal[:, :, 0:33] = xc @ W_x + b_x   (4096 x 33, K=1024, ldc=48)
    gemm_bias<true><<<dim3(1, 4096 / 64), 256, 0, stream>>>(
        xc, W_x, b_x, scal, 1024, 1024, 33, 48, 33);

    // 4. parallel log-space rates -> r, per-chunk products RP
    rates_par<<<NBATCH, 256, 0, stream>>>(scal, A_log, RP);

    // 5. phase A: local chunk scans -> S
    scan_states<<<dim3(DI / 128, NC, NBATCH), 128, 0, stream>>>(scal, xc, S);

    // 6. stitch chunk boundary states -> Hin
    stitch<<<dim3(DI / 256, NBATCH), 256, 0, stream>>>(S, RP, Hin);

    // 7. phase B: full scan, y = C.h + D*xc, gate with silu(res) -> xr cols [0:1024)
    scan_out<<<dim3(DI / 128, NC, NBATCH), 128, 0, stream>>>(scal, xc, Hin, Dw, xr);

    // 8. out = y_act @ W_out + b_out   (4096 x 512, K=1024, lda=2048)
    gemm_bias<false><<<dim3(512 / 64, 4096 / 64), 256, 0, stream>>>(
        xr, W_out, b_out, out, 1024, 2048, 512, 512, 512);
}

// Round 3
// 253.542 us; speedup vs baseline: 5.9678x; 1.6038x over previous
//
#include <hip/hip_runtime.h>
#include <hip/hip_bf16.h>
#include <cmath>

// ---------------------------------------------------------------------------
// Mamba block: bf16-MFMA GEMM1/GEMM2 + f32 small GEMM + chunked scan.
//   B=2, L=2048, D_MODEL=512, D_INNER=1024, D_STATE=16, D_CONV=4, EPS=1e-8
// Workspace layout (float units):
//   xr   : (B,L,2048)  = 8,388,608   x_inner cols[0:1024), res cols[1024:2048)
//   xc   : (B,L,1024)  = 4,194,304
//   scal : (B,L,48)    =   196,608   [0:16)=B_sel, [16:32)=C_sel, [32:48)=dt->r
//   S    : (B,16,16,1024) = 524,288
//   Hin  : (B,16,16,1024) = 524,288
//   RP   : (B,16,16)   =       512
//   xbf  : 4096x512  bf16 = 1,048,576 f
//   Wt1  : 2048x512  bf16 =   524,288 f   (W_in^T)
//   Wt2  : 512x1024  bf16 =   262,144 f   (W_out^T)
//   ybf  : 4096x1024 bf16 = 2,097,152 f   (y_act, A of GEMM2)
// ---------------------------------------------------------------------------

#define L_SEQ 2048
#define NBATCH 2
#define DI 1024
#define NC 16
#define LC 128
#define EPS_F 1e-8f
#define LOG_EPS -18.420680744f

typedef __attribute__((ext_vector_type(8))) __bf16 bf16x8;
typedef __attribute__((ext_vector_type(4))) float f32x4;

__device__ __forceinline__ float silu_f(float v) {
    return v / (1.f + __expf(-v));
}

__device__ __forceinline__ ushort bf16_bits(float v) {
    __hip_bfloat16 h = __float2bfloat16(v);
    return *reinterpret_cast<ushort*>(&h);
}

// ---------------- bf16 MFMA GEMM: C[M,N] = A[M,K] @ Bt[N,K]^T + bias -------
// A row-major M x K (bf16), Bt row-major N x K (bf16), C f32 ldc=N.
// 128x128 tile, BK=64, 4 waves (2x2 of 64x64), 16x16x32 MFMA, m97 structure.
__global__ __launch_bounds__(256) void gemm_mfma(
    const ushort* __restrict__ A, const ushort* __restrict__ Bt,
    const float* __restrict__ bias, float* __restrict__ C,
    int M, int N, int K)
{
    __shared__ ushort lA[128 * 64];
    __shared__ ushort lB[128 * 64];
    const int tid = threadIdx.x;
    const int w = tid >> 6, ln = tid & 63;
    const int wr = w >> 1, wc = w & 1;
    const int bm = blockIdx.y * 128, bn = blockIdx.x * 128;
    const int q = ln >> 4, r = ln & 15;
    f32x4 acc[4][4] = {};

    for (int k0 = 0; k0 < K; k0 += 64) {
        // stage 16 KB A-tile + 16 KB B-tile; 16 wave-chunks of 1 KB each side
        #pragma unroll
        for (int j = 0; j < 4; ++j) {
            int c = w * 4 + j;
            int i = c * 64 + ln;            // 16B-chunk index 0..1023
            int m = i >> 3, k8 = (i & 7) * 8;
            __builtin_amdgcn_global_load_lds(
                (const __attribute__((address_space(1))) void*)(A + (size_t)(bm + m) * K + k0 + k8),
                (__attribute__((address_space(3))) void*)(lA + (size_t)i * 8),
                16, 0, 0);
            __builtin_amdgcn_global_load_lds(
                (const __attribute__((address_space(1))) void*)(Bt + (size_t)(bn + m) * K + k0 + k8),
                (__attribute__((address_space(3))) void*)(lB + (size_t)i * 8),
                16, 0, 0);
        }
        __syncthreads();
        #pragma unroll
        for (int kk = 0; kk < 2; ++kk) {
            const int ko = kk * 32 + q * 8;
            bf16x8 af[4], bfr[4];
            #pragma unroll
            for (int m = 0; m < 4; ++m)
                af[m] = *reinterpret_cast<const bf16x8*>(&lA[(wr * 64 + m * 16 + r) * 64 + ko]);
            #pragma unroll
            for (int n = 0; n < 4; ++n)
                bfr[n] = *reinterpret_cast<const bf16x8*>(&lB[(wc * 64 + n * 16 + r) * 64 + ko]);
            #pragma unroll
            for (int m = 0; m < 4; ++m)
                #pragma unroll
                for (int n = 0; n < 4; ++n)
                    acc[m][n] = __builtin_amdgcn_mfma_f32_16x16x32_bf16(af[m], bfr[n], acc[m][n], 0, 0, 0);
        }
        __syncthreads();
    }

    // epilogue: C/D layout col=lane&15, row=(lane>>4)*4+j
    #pragma unroll
    for (int n = 0; n < 4; ++n) {
        int col = bn + wc * 64 + n * 16 + r;
        float bv = bias[col];
        #pragma unroll
        for (int m = 0; m < 4; ++m) {
            int row0 = bm + wr * 64 + m * 16 + q * 4;
            #pragma unroll
            for (int j = 0; j < 4; ++j)
                C[(size_t)(row0 + j) * N + col] = acc[m][n][j] + bv;
        }
    }
}

// ---------------- elementwise f32 -> bf16 cast -----------------------------
__global__ __launch_bounds__(256) void cast_bf16(
    const float* __restrict__ src, ushort* __restrict__ dst, int n4)
{
    int i = blockIdx.x * 256 + threadIdx.x;
    if (i >= n4) return;
    float4 v = *reinterpret_cast<const float4*>(src + (size_t)i * 4);
    ushort4 o;
    o.x = bf16_bits(v.x); o.y = bf16_bits(v.y);
    o.z = bf16_bits(v.z); o.w = bf16_bits(v.w);
    *reinterpret_cast<ushort4*>(dst + (size_t)i * 4) = o;
}

// ---------------- transpose + cast: src[R,C] f32 -> dst[C,R] bf16 ----------
__global__ __launch_bounds__(256) void tcast_bf16(
    const float* __restrict__ src, ushort* __restrict__ dst, int R, int Ccols)
{
    __shared__ float ld[64][65];
    int r0 = blockIdx.y * 64, c0 = blockIdx.x * 64;
    #pragma unroll
    for (int i = 0; i < 16; ++i) {
        int idx = threadIdx.x + i * 256;
        int rr = idx >> 6, cc = idx & 63;
        ld[rr][cc] = src[(size_t)(r0 + rr) * Ccols + c0 + cc];
    }
    __syncthreads();
    #pragma unroll
    for (int i = 0; i < 16; ++i) {
        int idx = threadIdx.x + i * 256;
        int cc = idx >> 6, rr = idx & 63;
        dst[(size_t)(c0 + cc) * R + r0 + rr] = bf16_bits(ld[rr][cc]);
    }
}

// ---------------- generic 64x64 tiled f32 GEMM with bias (GEMM3 only) ------
template<bool NG>
__global__ __launch_bounds__(256) void gemm_bias(
    const float* __restrict__ A, const float* __restrict__ B,
    const float* __restrict__ bias, float* __restrict__ C,
    int K, int lda, int ldb, int ldc, int Nvalid)
{
    __shared__ float As[16][68];
    __shared__ float Bs[16][68];
    const int tid = threadIdx.x;
    const int tx = tid & 15, ty = tid >> 4;
    const int bm = blockIdx.y * 64, bn = blockIdx.x * 64;
    const int am = tid >> 2, ak = (tid & 3) * 4;
    const int bk = tid >> 4, bn4 = (tid & 15) * 4;
    float acc[4][4] = {};
    const float* Ap = A + (long)(bm + am) * lda + ak;

    for (int k0 = 0; k0 < K; k0 += 16) {
        float4 av = *reinterpret_cast<const float4*>(Ap + k0);
        As[ak + 0][am] = av.x; As[ak + 1][am] = av.y;
        As[ak + 2][am] = av.z; As[ak + 3][am] = av.w;
        if (NG) {
            #pragma unroll
            for (int j = 0; j < 4; ++j) {
                int n = bn + bn4 + j;
                Bs[bk][bn4 + j] = (n < Nvalid) ? B[(long)(k0 + bk) * ldb + n] : 0.f;
            }
        } else {
            float4 bv = *reinterpret_cast<const float4*>(B + (long)(k0 + bk) * ldb + bn + bn4);
            Bs[bk][bn4 + 0] = bv.x; Bs[bk][bn4 + 1] = bv.y;
            Bs[bk][bn4 + 2] = bv.z; Bs[bk][bn4 + 3] = bv.w;
        }
        __syncthreads();
        #pragma unroll
        for (int k = 0; k < 16; ++k) {
            float a[4], b[4];
            *reinterpret_cast<float4*>(a) = *reinterpret_cast<const float4*>(&As[k][ty * 4]);
            *reinterpret_cast<float4*>(b) = *reinterpret_cast<const float4*>(&Bs[k][tx * 4]);
            #pragma unroll
            for (int i = 0; i < 4; ++i)
                #pragma unroll
                for (int j = 0; j < 4; ++j)
                    acc[i][j] = fmaf(a[i], b[j], acc[i][j]);
        }
        __syncthreads();
    }

    #pragma unroll
    for (int i = 0; i < 4; ++i) {
        int gm = bm + ty * 4 + i;
        if (NG) {
            #pragma unroll
            for (int j = 0; j < 4; ++j) {
                int gn = bn + tx * 4 + j;
                if (gn < Nvalid) C[(long)gm * ldc + gn] = acc[i][j] + bias[gn];
            }
        } else {
            int gn = bn + tx * 4;
            float4 o;
            o.x = acc[i][0] + bias[gn + 0];
            o.y = acc[i][1] + bias[gn + 1];
            o.z = acc[i][2] + bias[gn + 2];
            o.w = acc[i][3] + bias[gn + 3];
            *reinterpret_cast<float4*>(C + (long)gm * ldc + gn) = o;
        }
    }
}

// ---------------- depthwise causal conv(4) + SiLU --------------------------
__global__ __launch_bounds__(256) void conv_silu(
    const float* __restrict__ xr, const float* __restrict__ cw,
    const float* __restrict__ cb, float* __restrict__ xc)
{
    int idx = blockIdx.x * 256 + threadIdx.x;
    int d = idx & (DI - 1);
    int l = (idx >> 10) & (L_SEQ - 1);
    float4 w = *reinterpret_cast<const float4*>(cw + d * 4);
    float acc = cb[d];
    long base = ((long)(idx >> 10)) * 2048 + d;
    if (l >= 3) acc = fmaf(xr[base - 3 * 2048], w.x, acc);
    if (l >= 2) acc = fmaf(xr[base - 2 * 2048], w.y, acc);
    if (l >= 1) acc = fmaf(xr[base - 1 * 2048], w.z, acc);
    acc = fmaf(xr[base], w.w, acc);
    xc[idx] = silu_f(acc);
}

// ---------------- parallel rates via log-space scan ------------------------
__global__ __launch_bounds__(256) void rates_par(
    float* __restrict__ scal, const float* __restrict__ A_log,
    float* __restrict__ RP)
{
    int b = blockIdx.x;
    int t = threadIdx.x;
    __shared__ float cdt[L_SEQ];
    __shared__ float wsum[4];
    __shared__ float An[16];
    if (t < 16) An[t] = -__expf(A_log[t]);
    float* base = scal + (long)b * L_SEQ * 48;

    float dt[8];
    float run = 0.f;
    const int l0 = t * 8;
    #pragma unroll
    for (int i = 0; i < 8; ++i) {
        float raw = base[(l0 + i) * 48 + 32];
        float d = (raw > 20.f) ? raw : log1pf(__expf(raw));
        dt[i] = d;
        run += d;
        cdt[l0 + i] = run;
    }

    float x = run;
    int lane = t & 63;
    #pragma unroll
    for (int d = 1; d < 64; d <<= 1) {
        float v = __shfl_up(x, d, 64);
        if (lane >= d) x += v;
    }
    int w = t >> 6;
    if (lane == 63) wsum[w] = x;
    __syncthreads();
    float woff = 0.f;
    for (int i = 0; i < w; ++i) woff += wsum[i];
    float toff = woff + x - run;
    #pragma unroll
    for (int i = 0; i < 8; ++i) cdt[l0 + i] += toff;
    __syncthreads();

    float cprev = (l0 == 0) ? 0.f : cdt[l0 - 1];
    #pragma unroll
    for (int i = 0; i < 8; ++i) {
        int l = l0 + i;
        float cl = cdt[l];
        float rv[16];
        #pragma unroll
        for (int s = 0; s < 16; ++s) {
            float A = An[s];
            float rr;
            if (A * cl >= LOG_EPS) {
                rr = __expf(A * dt[i]);
            } else {
                float lp = A * cprev;
                rr = (lp >= LOG_EPS) ? EPS_F / __expf(lp) : 1.f;
            }
            rv[s] = rr;
        }
        float4* dst = reinterpret_cast<float4*>(base + l * 48 + 32);
        dst[0] = *reinterpret_cast<float4*>(&rv[0]);
        dst[1] = *reinterpret_cast<float4*>(&rv[4]);
        dst[2] = *reinterpret_cast<float4*>(&rv[8]);
        dst[3] = *reinterpret_cast<float4*>(&rv[12]);
        cprev = cl;
    }

    if ((t & 15) == 15) {
        int c = t >> 4;
        float ce = cdt[c * LC + LC - 1];
        float cp = (c == 0) ? 0.f : cdt[c * LC - 1];
        for (int s = 0; s < 16; ++s) {
            float A = An[s];
            float pe = fmaxf(__expf(A * ce), EPS_F);
            float pp = fmaxf(__expf(A * cp), EPS_F);
            RP[(b * NC + c) * 16 + s] = pe / pp;
        }
    }
}

// ---------------- phase A: per-chunk local end states ----------------------
__global__ __launch_bounds__(128) void scan_states(
    const float* __restrict__ scal, const float* __restrict__ xc,
    float* __restrict__ S)
{
    int b = blockIdx.z, c = blockIdx.y;
    int d = blockIdx.x * 128 + threadIdx.x;
    __shared__ float sc[LC * 48];
    const float4* src = reinterpret_cast<const float4*>(scal + ((long)(b * L_SEQ) + c * LC) * 48);
    float4* dst = reinterpret_cast<float4*>(sc);
    for (int i = threadIdx.x; i < LC * 48 / 4; i += 128) dst[i] = src[i];
    __syncthreads();
    float h[16];
    #pragma unroll
    for (int s = 0; s < 16; ++s) h[s] = 0.f;
    const float* xcp = xc + ((long)(b * L_SEQ) + c * LC) * 1024 + d;
    for (int ll = 0; ll < LC; ++ll) {
        float xcv = xcp[(long)ll * 1024];
        const float* e = sc + ll * 48;
        #pragma unroll
        for (int s = 0; s < 16; ++s) h[s] = fmaf(e[32 + s], h[s], e[s] * xcv);
    }
    float* Sp = S + ((long)(b * NC + c) * 16) * 1024 + d;
    #pragma unroll
    for (int s = 0; s < 16; ++s) Sp[(long)s * 1024] = h[s];
}

// ---------------- stitch: chunk-boundary states ----------------------------
__global__ __launch_bounds__(256) void stitch(
    const float* __restrict__ S, const float* __restrict__ RP,
    float* __restrict__ Hin)
{
    int b = blockIdx.y;
    int d = blockIdx.x * 256 + threadIdx.x;
    float H[16];
    #pragma unroll
    for (int s = 0; s < 16; ++s) H[s] = 0.f;
    for (int c = 0; c < NC; ++c) {
        long off = ((long)(b * NC + c) * 16) * 1024 + d;
        #pragma unroll
        for (int s = 0; s < 16; ++s) Hin[off + (long)s * 1024] = H[s];
        #pragma unroll
        for (int s = 0; s < 16; ++s)
            H[s] = fmaf(RP[(b * NC + c) * 16 + s], H[s], S[off + (long)s * 1024]);
    }
}

// ---------------- phase B: full scan + y + gating -> bf16 ------------------
__global__ __launch_bounds__(128) void scan_out(
    const float* __restrict__ scal, const float* __restrict__ xc,
    const float* __restrict__ Hin, const float* __restrict__ Dw,
    const float* __restrict__ xr, ushort* __restrict__ ybf)
{
    int b = blockIdx.z, c = blockIdx.y;
    int d = blockIdx.x * 128 + threadIdx.x;
    __shared__ float sc[LC * 48];
    const float4* src = reinterpret_cast<const float4*>(scal + ((long)(b * L_SEQ) + c * LC) * 48);
    float4* dst = reinterpret_cast<float4*>(sc);
    for (int i = threadIdx.x; i < LC * 48 / 4; i += 128) dst[i] = src[i];
    __syncthreads();
    float h[16];
    long hoff = ((long)(b * NC + c) * 16) * 1024 + d;
    #pragma unroll
    for (int s = 0; s < 16; ++s) h[s] = Hin[hoff + (long)s * 1024];
    float Dd = Dw[d];
    for (int ll = 0; ll < LC; ++ll) {
        long row = (long)(b * L_SEQ) + c * LC + ll;
        float xcv = xc[row * 1024 + d];
        float resv = xr[row * 2048 + 1024 + d];
        const float* e = sc + ll * 48;
        float y = 0.f;
        #pragma unroll
        for (int s = 0; s < 16; ++s) {
            h[s] = fmaf(e[32 + s], h[s], e[s] * xcv);
            y = fmaf(e[16 + s], h[s], y);
        }
        y = fmaf(Dd, xcv, y);
        ybf[row * 1024 + d] = bf16_bits(y * silu_f(resv));
    }
}

// ---------------------------------------------------------------------------
extern "C" void kernel_launch(void* const* d_in, const int* in_sizes, int n_in,
                              void* d_out, int out_size, void* d_ws, size_t ws_size,
                              hipStream_t stream)
{
    const float* x      = (const float*)d_in[0];
    const float* W_in   = (const float*)d_in[1];
    const float* b_in   = (const float*)d_in[2];
    const float* conv_w = (const float*)d_in[3];
    const float* conv_b = (const float*)d_in[4];
    const float* W_x    = (const float*)d_in[5];
    const float* b_x    = (const float*)d_in[6];
    const float* A_log  = (const float*)d_in[7];
    const float* Dw     = (const float*)d_in[8];
    const float* W_out  = (const float*)d_in[9];
    const float* b_out  = (const float*)d_in[10];
    float* out = (float*)d_out;

    float* ws   = (float*)d_ws;
    float* xr   = ws;                        // 8,388,608
    float* xc   = xr + 8388608;              // 4,194,304
    float* scal = xc + 4194304;              //   196,608
    float* S    = scal + 196608;             //   524,288
    float* Hin  = S + 524288;                //   524,288
    float* RP   = Hin + 524288;              //       512
    ushort* xbf = (ushort*)(RP + 512);       // 4096x512
    ushort* Wt1 = xbf + 2097152;             // 2048x512
    ushort* Wt2 = Wt1 + 1048576;             // 512x1024
    ushort* ybf = Wt2 + 524288;              // 4096x1024

    // 0. casts
    cast_bf16<<<(4096 * 512 / 4 + 255) / 256, 256, 0, stream>>>(x, xbf, 4096 * 512 / 4);
    tcast_bf16<<<dim3(2048 / 64, 512 / 64), 256, 0, stream>>>(W_in, Wt1, 512, 2048);
    tcast_bf16<<<dim3(512 / 64, 1024 / 64), 256, 0, stream>>>(W_out, Wt2, 1024, 512);

    // 1. xr = x @ W_in + b_in  (MFMA bf16: M=4096, N=2048, K=512)
    gemm_mfma<<<dim3(2048 / 128, 4096 / 128), 256, 0, stream>>>(
        xbf, Wt1, b_in, xr, 4096, 2048, 512);

    // 2. xc = silu(depthwise_conv(x_inner))
    conv_silu<<<(NBATCH * L_SEQ * DI) / 256, 256, 0, stream>>>(xr, conv_w, conv_b, xc);

    // 3. scal[:, :, 0:33] = xc @ W_x + b_x   (f32, N=33)
    gemm_bias<true><<<dim3(1, 4096 / 64), 256, 0, stream>>>(
        xc, W_x, b_x, scal, 1024, 1024, 33, 48, 33);

    // 4. parallel log-space rates
    rates_par<<<NBATCH, 256, 0, stream>>>(scal, A_log, RP);

    // 5-7. chunked scan
    scan_states<<<dim3(DI / 128, NC, NBATCH), 128, 0, stream>>>(scal, xc, S);
    stitch<<<dim3(DI / 256, NBATCH), 256, 0, stream>>>(S, RP, Hin);
    scan_out<<<dim3(DI / 128, NC, NBATCH), 128, 0, stream>>>(scal, xc, Hin, Dw, xr, ybf);

    // 8. out = y_act @ W_out + b_out  (MFMA bf16: M=4096, N=512, K=1024)
    gemm_mfma<<<dim3(512 / 128, 4096 / 128), 256, 0, stream>>>(
        ybf, Wt2, b_out, out, 4096, 512, 1024);
}

// Round 4
// 192.934 us; speedup vs baseline: 7.8425x; 1.3141x over previous
//
#include <hip/hip_runtime.h>
#include <hip/hip_bf16.h>
#include <cmath>

// ---------------------------------------------------------------------------
// Mamba block: bf16-MFMA GEMM1/GEMM2/GEMM3(B,C) + f32 dt matvec + chunked scan.
//   B=2, L=2048, D_MODEL=512, D_INNER=1024, D_STATE=16, D_CONV=4, EPS=1e-8
// Workspace layout (float units), ~71 MB total (same as round 3):
//   xr   : (B,L,2048)  = 8,388,608
//   xc   : (B,L,1024)  = 4,194,304
//   scal : (B,L,48)    =   196,608
//   S    : 524,288   Hin : 524,288   RP : 512
//   xbf  region: 1,048,576 f  = x bf16 (GEMM1); after GEMM1 reused as
//                P (524,288 f) + Wxt (16,384 f)
//   Wt1  : 524,288 f (W_in^T bf16)
//   Wt2  : 262,144 f (W_out^T bf16)
//   ybf  region: 2,097,152 f = xcb (bf16 xc, GEMM3 A) then y_act bf16 (GEMM2 A)
// ---------------------------------------------------------------------------

#define L_SEQ 2048
#define NBATCH 2
#define DI 1024
#define NC 16
#define LC 128
#define EPS_F 1e-8f
#define LOG_EPS -18.420680744f

typedef __attribute__((ext_vector_type(8))) __bf16 bf16x8;
typedef __attribute__((ext_vector_type(4))) float f32x4;

__device__ __forceinline__ float silu_f(float v) {
    return v / (1.f + __expf(-v));
}

__device__ __forceinline__ ushort bf16_bits(float v) {
    __hip_bfloat16 h = __float2bfloat16(v);
    return *reinterpret_cast<ushort*>(&h);
}

// ---------------- bf16 MFMA GEMM: C[M,N] = A[M,K] @ Bt[N,K]^T + bias -------
__global__ __launch_bounds__(256) void gemm_mfma(
    const ushort* __restrict__ A, const ushort* __restrict__ Bt,
    const float* __restrict__ bias, float* __restrict__ C,
    int M, int N, int K)
{
    __shared__ ushort lA[128 * 64];
    __shared__ ushort lB[128 * 64];
    const int tid = threadIdx.x;
    const int w = tid >> 6, ln = tid & 63;
    const int wr = w >> 1, wc = w & 1;
    const int bm = blockIdx.y * 128, bn = blockIdx.x * 128;
    const int q = ln >> 4, r = ln & 15;
    f32x4 acc[4][4] = {};

    for (int k0 = 0; k0 < K; k0 += 64) {
        #pragma unroll
        for (int j = 0; j < 4; ++j) {
            int c = w * 4 + j;
            int i = c * 64 + ln;
            int m = i >> 3, k8 = (i & 7) * 8;
            __builtin_amdgcn_global_load_lds(
                (const __attribute__((address_space(1))) void*)(A + (size_t)(bm + m) * K + k0 + k8),
                (__attribute__((address_space(3))) void*)(lA + (size_t)i * 8),
                16, 0, 0);
            __builtin_amdgcn_global_load_lds(
                (const __attribute__((address_space(1))) void*)(Bt + (size_t)(bn + m) * K + k0 + k8),
                (__attribute__((address_space(3))) void*)(lB + (size_t)i * 8),
                16, 0, 0);
        }
        __syncthreads();
        #pragma unroll
        for (int kk = 0; kk < 2; ++kk) {
            const int ko = kk * 32 + q * 8;
            bf16x8 af[4], bfr[4];
            #pragma unroll
            for (int m = 0; m < 4; ++m)
                af[m] = *reinterpret_cast<const bf16x8*>(&lA[(wr * 64 + m * 16 + r) * 64 + ko]);
            #pragma unroll
            for (int n = 0; n < 4; ++n)
                bfr[n] = *reinterpret_cast<const bf16x8*>(&lB[(wc * 64 + n * 16 + r) * 64 + ko]);
            #pragma unroll
            for (int m = 0; m < 4; ++m)
                #pragma unroll
                for (int n = 0; n < 4; ++n)
                    acc[m][n] = __builtin_amdgcn_mfma_f32_16x16x32_bf16(af[m], bfr[n], acc[m][n], 0, 0, 0);
        }
        __syncthreads();
    }

    #pragma unroll
    for (int n = 0; n < 4; ++n) {
        int col = bn + wc * 64 + n * 16 + r;
        float bv = bias[col];
        #pragma unroll
        for (int m = 0; m < 4; ++m) {
            int row0 = bm + wr * 64 + m * 16 + q * 4;
            #pragma unroll
            for (int j = 0; j < 4; ++j)
                C[(size_t)(row0 + j) * N + col] = acc[m][n][j] + bv;
        }
    }
}

// ---------------- GEMM3 partials: P[ks][4096][32] = xcb @ Wxt^T ------------
// A = xcb (4096 x 1024 bf16), Bt = Wxt (32 x 1024 bf16). 64x32 tile, K=256/ks.
__global__ __launch_bounds__(256) void gemm3_mfma(
    const ushort* __restrict__ A, const ushort* __restrict__ Bt,
    float* __restrict__ P)
{
    __shared__ ushort lA[64 * 64];
    __shared__ ushort lB[32 * 64];
    const int t = threadIdx.x;
    const int w = t >> 6, ln = t & 63;
    const int q = ln >> 4, r = ln & 15;
    const int bm = blockIdx.y * 64;
    const int ks = blockIdx.x;
    f32x4 a0 = {}, a1 = {};

    for (int k0 = ks * 256; k0 < ks * 256 + 256; k0 += 64) {
        #pragma unroll
        for (int jj = 0; jj < 2; ++jj) {
            int i = t + jj * 256;
            int m = i >> 3, k8 = (i & 7) * 8;
            __builtin_amdgcn_global_load_lds(
                (const __attribute__((address_space(1))) void*)(A + (size_t)(bm + m) * 1024 + k0 + k8),
                (__attribute__((address_space(3))) void*)(lA + (size_t)i * 8),
                16, 0, 0);
        }
        {
            int m = t >> 3, k8 = (t & 7) * 8;
            __builtin_amdgcn_global_load_lds(
                (const __attribute__((address_space(1))) void*)(Bt + (size_t)m * 1024 + k0 + k8),
                (__attribute__((address_space(3))) void*)(lB + (size_t)t * 8),
                16, 0, 0);
        }
        __syncthreads();
        #pragma unroll
        for (int kk = 0; kk < 2; ++kk) {
            const int ko = kk * 32 + q * 8;
            bf16x8 af = *reinterpret_cast<const bf16x8*>(&lA[(w * 16 + r) * 64 + ko]);
            bf16x8 b0 = *reinterpret_cast<const bf16x8*>(&lB[(r) * 64 + ko]);
            bf16x8 b1 = *reinterpret_cast<const bf16x8*>(&lB[(16 + r) * 64 + ko]);
            a0 = __builtin_amdgcn_mfma_f32_16x16x32_bf16(af, b0, a0, 0, 0, 0);
            a1 = __builtin_amdgcn_mfma_f32_16x16x32_bf16(af, b1, a1, 0, 0, 0);
        }
        __syncthreads();
    }

    const int row0 = bm + w * 16 + q * 4;
    const size_t base = (size_t)ks * 131072;
    #pragma unroll
    for (int j = 0; j < 4; ++j) {
        P[base + (size_t)(row0 + j) * 32 + r]      = a0[j];
        P[base + (size_t)(row0 + j) * 32 + 16 + r] = a1[j];
    }
}

// ---------------- GEMM3 reduce: scal[l][c] = bias[c] + sum_ks P ------------
__global__ __launch_bounds__(256) void gemm3_reduce(
    const float* __restrict__ P, const float* __restrict__ b_x,
    float* __restrict__ scal)
{
    int idx = blockIdx.x * 256 + threadIdx.x;     // < 131072
    int l = idx >> 5, c = idx & 31;
    float v = b_x[c] + P[idx] + P[idx + 131072] + P[idx + 262144] + P[idx + 393216];
    scal[(size_t)l * 48 + c] = v;
}

// ---------------- dt column (f32): scal[l][32] = xc[l]·W_x[:,32] + b -------
__global__ __launch_bounds__(256) void dt_matvec(
    const float* __restrict__ xc, const float* __restrict__ W_x,
    const float* __restrict__ b_x, float* __restrict__ scal)
{
    __shared__ float wcol[1024];
    const int t = threadIdx.x;
    #pragma unroll
    for (int i = 0; i < 4; ++i) wcol[t + i * 256] = W_x[(size_t)(t + i * 256) * 33 + 32];
    __syncthreads();
    const int wv = t >> 6, ln = t & 63;
    const size_t row = (size_t)blockIdx.x * 4 + wv;
    const float* xp = xc + row * 1024;
    float acc = 0.f;
    #pragma unroll
    for (int j = 0; j < 16; ++j) acc = fmaf(xp[ln + j * 64], wcol[ln + j * 64], acc);
    #pragma unroll
    for (int off = 32; off; off >>= 1) acc += __shfl_xor(acc, off, 64);
    if (ln == 0) scal[row * 48 + 32] = acc + b_x[32];
}

// ---------------- casts -----------------------------------------------------
__global__ __launch_bounds__(256) void cast_bf16(
    const float* __restrict__ src, ushort* __restrict__ dst, int n4)
{
    int i = blockIdx.x * 256 + threadIdx.x;
    if (i >= n4) return;
    float4 v = *reinterpret_cast<const float4*>(src + (size_t)i * 4);
    ushort4 o;
    o.x = bf16_bits(v.x); o.y = bf16_bits(v.y);
    o.z = bf16_bits(v.z); o.w = bf16_bits(v.w);
    *reinterpret_cast<ushort4*>(dst + (size_t)i * 4) = o;
}

__global__ __launch_bounds__(256) void tcast_bf16(
    const float* __restrict__ src, ushort* __restrict__ dst, int R, int Ccols)
{
    __shared__ float ld[64][65];
    int r0 = blockIdx.y * 64, c0 = blockIdx.x * 64;
    #pragma unroll
    for (int i = 0; i < 16; ++i) {
        int idx = threadIdx.x + i * 256;
        int rr = idx >> 6, cc = idx & 63;
        ld[rr][cc] = src[(size_t)(r0 + rr) * Ccols + c0 + cc];
    }
    __syncthreads();
    #pragma unroll
    for (int i = 0; i < 16; ++i) {
        int idx = threadIdx.x + i * 256;
        int cc = idx >> 6, rr = idx & 63;
        dst[(size_t)(c0 + cc) * R + r0 + rr] = bf16_bits(ld[rr][cc]);
    }
}

// Wxt[c][k] = bf16(W_x[k][c]) for c < 32
__global__ __launch_bounds__(256) void wxt_cast(
    const float* __restrict__ W_x, ushort* __restrict__ Wxt)
{
    int idx = blockIdx.x * 256 + threadIdx.x;     // < 32768
    int c = idx >> 10, k = idx & 1023;
    Wxt[idx] = bf16_bits(W_x[(size_t)k * 33 + c]);
}

// ---------------- depthwise causal conv(4) + SiLU (f32 + bf16 out) ---------
__global__ __launch_bounds__(256) void conv_silu(
    const float* __restrict__ xr, const float* __restrict__ cw,
    const float* __restrict__ cb, float* __restrict__ xc,
    ushort* __restrict__ xcb)
{
    int idx = blockIdx.x * 256 + threadIdx.x;
    int d = idx & (DI - 1);
    int l = (idx >> 10) & (L_SEQ - 1);
    float4 w = *reinterpret_cast<const float4*>(cw + d * 4);
    float acc = cb[d];
    long base = ((long)(idx >> 10)) * 2048 + d;
    if (l >= 3) acc = fmaf(xr[base - 3 * 2048], w.x, acc);
    if (l >= 2) acc = fmaf(xr[base - 2 * 2048], w.y, acc);
    if (l >= 1) acc = fmaf(xr[base - 1 * 2048], w.z, acc);
    acc = fmaf(xr[base], w.w, acc);
    float v = silu_f(acc);
    xc[idx] = v;
    xcb[idx] = bf16_bits(v);
}

// ---------------- parallel rates via log-space scan ------------------------
__global__ __launch_bounds__(256) void rates_par(
    float* __restrict__ scal, const float* __restrict__ A_log,
    float* __restrict__ RP)
{
    int b = blockIdx.x;
    int t = threadIdx.x;
    __shared__ float cdt[L_SEQ];
    __shared__ float wsum[4];
    __shared__ float An[16];
    if (t < 16) An[t] = -__expf(A_log[t]);
    float* base = scal + (long)b * L_SEQ * 48;

    float dt[8];
    float run = 0.f;
    const int l0 = t * 8;
    #pragma unroll
    for (int i = 0; i < 8; ++i) {
        float raw = base[(l0 + i) * 48 + 32];
        float d = (raw > 20.f) ? raw : log1pf(__expf(raw));
        dt[i] = d;
        run += d;
        cdt[l0 + i] = run;
    }

    float x = run;
    int lane = t & 63;
    #pragma unroll
    for (int d = 1; d < 64; d <<= 1) {
        float v = __shfl_up(x, d, 64);
        if (lane >= d) x += v;
    }
    int w = t >> 6;
    if (lane == 63) wsum[w] = x;
    __syncthreads();
    float woff = 0.f;
    for (int i = 0; i < w; ++i) woff += wsum[i];
    float toff = woff + x - run;
    #pragma unroll
    for (int i = 0; i < 8; ++i) cdt[l0 + i] += toff;
    __syncthreads();

    float cprev = (l0 == 0) ? 0.f : cdt[l0 - 1];
    #pragma unroll
    for (int i = 0; i < 8; ++i) {
        int l = l0 + i;
        float cl = cdt[l];
        float rv[16];
        #pragma unroll
        for (int s = 0; s < 16; ++s) {
            float A = An[s];
            float rr;
            if (A * cl >= LOG_EPS) {
                rr = __expf(A * dt[i]);
            } else {
                float lp = A * cprev;
                rr = (lp >= LOG_EPS) ? EPS_F / __expf(lp) : 1.f;
            }
            rv[s] = rr;
        }
        float4* dst = reinterpret_cast<float4*>(base + l * 48 + 32);
        dst[0] = *reinterpret_cast<float4*>(&rv[0]);
        dst[1] = *reinterpret_cast<float4*>(&rv[4]);
        dst[2] = *reinterpret_cast<float4*>(&rv[8]);
        dst[3] = *reinterpret_cast<float4*>(&rv[12]);
        cprev = cl;
    }

    if ((t & 15) == 15) {
        int c = t >> 4;
        float ce = cdt[c * LC + LC - 1];
        float cp = (c == 0) ? 0.f : cdt[c * LC - 1];
        for (int s = 0; s < 16; ++s) {
            float A = An[s];
            float pe = fmaxf(__expf(A * ce), EPS_F);
            float pp = fmaxf(__expf(A * cp), EPS_F);
            RP[(b * NC + c) * 16 + s] = pe / pp;
        }
    }
}

// ---------------- phase A: per-chunk local end states ----------------------
__global__ __launch_bounds__(128) void scan_states(
    const float* __restrict__ scal, const float* __restrict__ xc,
    float* __restrict__ S)
{
    int b = blockIdx.z, c = blockIdx.y;
    int d = blockIdx.x * 128 + threadIdx.x;
    __shared__ float sc[LC * 48];
    const float4* src = reinterpret_cast<const float4*>(scal + ((long)(b * L_SEQ) + c * LC) * 48);
    float4* dst = reinterpret_cast<float4*>(sc);
    for (int i = threadIdx.x; i < LC * 48 / 4; i += 128) dst[i] = src[i];
    __syncthreads();
    float h[16];
    #pragma unroll
    for (int s = 0; s < 16; ++s) h[s] = 0.f;
    const float* xcp = xc + ((long)(b * L_SEQ) + c * LC) * 1024 + d;
    for (int ll = 0; ll < LC; ++ll) {
        float xcv = xcp[(long)ll * 1024];
        const float* e = sc + ll * 48;
        #pragma unroll
        for (int s = 0; s < 16; ++s) h[s] = fmaf(e[32 + s], h[s], e[s] * xcv);
    }
    float* Sp = S + ((long)(b * NC + c) * 16) * 1024 + d;
    #pragma unroll
    for (int s = 0; s < 16; ++s) Sp[(long)s * 1024] = h[s];
}

// ---------------- stitch: chunk-boundary states ----------------------------
__global__ __launch_bounds__(256) void stitch(
    const float* __restrict__ S, const float* __restrict__ RP,
    float* __restrict__ Hin)
{
    int b = blockIdx.y;
    int d = blockIdx.x * 256 + threadIdx.x;
    float H[16];
    #pragma unroll
    for (int s = 0; s < 16; ++s) H[s] = 0.f;
    for (int c = 0; c < NC; ++c) {
        long off = ((long)(b * NC + c) * 16) * 1024 + d;
        #pragma unroll
        for (int s = 0; s < 16; ++s) Hin[off + (long)s * 1024] = H[s];
        #pragma unroll
        for (int s = 0; s < 16; ++s)
            H[s] = fmaf(RP[(b * NC + c) * 16 + s], H[s], S[off + (long)s * 1024]);
    }
}

// ---------------- phase B: full scan + y + gating -> bf16 ------------------
__global__ __launch_bounds__(128) void scan_out(
    const float* __restrict__ scal, const float* __restrict__ xc,
    const float* __restrict__ Hin, const float* __restrict__ Dw,
    const float* __restrict__ xr, ushort* __restrict__ ybf)
{
    int b = blockIdx.z, c = blockIdx.y;
    int d = blockIdx.x * 128 + threadIdx.x;
    __shared__ float sc[LC * 48];
    const float4* src = reinterpret_cast<const float4*>(scal + ((long)(b * L_SEQ) + c * LC) * 48);
    float4* dst = reinterpret_cast<float4*>(sc);
    for (int i = threadIdx.x; i < LC * 48 / 4; i += 128) dst[i] = src[i];
    __syncthreads();
    float h[16];
    long hoff = ((long)(b * NC + c) * 16) * 1024 + d;
    #pragma unroll
    for (int s = 0; s < 16; ++s) h[s] = Hin[hoff + (long)s * 1024];
    float Dd = Dw[d];
    for (int ll = 0; ll < LC; ++ll) {
        long row = (long)(b * L_SEQ) + c * LC + ll;
        float xcv = xc[row * 1024 + d];
        float resv = xr[row * 2048 + 1024 + d];
        const float* e = sc + ll * 48;
        float y = 0.f;
        #pragma unroll
        for (int s = 0; s < 16; ++s) {
            h[s] = fmaf(e[32 + s], h[s], e[s] * xcv);
            y = fmaf(e[16 + s], h[s], y);
        }
        y = fmaf(Dd, xcv, y);
        ybf[row * 1024 + d] = bf16_bits(y * silu_f(resv));
    }
}

// ---------------------------------------------------------------------------
extern "C" void kernel_launch(void* const* d_in, const int* in_sizes, int n_in,
                              void* d_out, int out_size, void* d_ws, size_t ws_size,
                              hipStream_t stream)
{
    const float* x      = (const float*)d_in[0];
    const float* W_in   = (const float*)d_in[1];
    const float* b_in   = (const float*)d_in[2];
    const float* conv_w = (const float*)d_in[3];
    const float* conv_b = (const float*)d_in[4];
    const float* W_x    = (const float*)d_in[5];
    const float* b_x    = (const float*)d_in[6];
    const float* A_log  = (const float*)d_in[7];
    const float* Dw     = (const float*)d_in[8];
    const float* W_out  = (const float*)d_in[9];
    const float* b_out  = (const float*)d_in[10];
    float* out = (float*)d_out;

    float* ws   = (float*)d_ws;
    float* xr   = ws;                        // 8,388,608
    float* xc   = xr + 8388608;              // 4,194,304
    float* scal = xc + 4194304;              //   196,608
    float* S    = scal + 196608;             //   524,288
    float* Hin  = S + 524288;                //   524,288
    float* RP   = Hin + 524288;              //       512
    ushort* xbf = (ushort*)(RP + 512);       // region: 1,048,576 f
    float*  P   = (float*)xbf;               //   alias (post-GEMM1): 524,288 f
    ushort* Wxt = (ushort*)(P + 524288);     //   alias (post-GEMM1): 32,768 u
    ushort* Wt1 = xbf + 2097152;             // 1,048,576 u -> 524,288 f
    ushort* Wt2 = Wt1 + 1048576;             //   524,288 u -> 262,144 f
    ushort* ybf = Wt2 + 524288;              // region: 4,194,304 u
    ushort* xcb = ybf;                       //   alias (pre-scan_out)

    // 0. input casts
    cast_bf16<<<(4096 * 512 / 4 + 255) / 256, 256, 0, stream>>>(x, xbf, 4096 * 512 / 4);
    tcast_bf16<<<dim3(2048 / 64, 512 / 64), 256, 0, stream>>>(W_in, Wt1, 512, 2048);
    tcast_bf16<<<dim3(512 / 64, 1024 / 64), 256, 0, stream>>>(W_out, Wt2, 1024, 512);

    // 1. xr = x @ W_in + b_in  (MFMA bf16: M=4096, N=2048, K=512)
    gemm_mfma<<<dim3(2048 / 128, 4096 / 128), 256, 0, stream>>>(
        xbf, Wt1, b_in, xr, 4096, 2048, 512);

    // 1b. Wxt = W_x[:, 0:32]^T bf16  (writes into xbf region — after GEMM1)
    wxt_cast<<<32768 / 256, 256, 0, stream>>>(W_x, Wxt);

    // 2. xc = silu(conv(x_inner))  (f32 + bf16 copies)
    conv_silu<<<(NBATCH * L_SEQ * DI) / 256, 256, 0, stream>>>(xr, conv_w, conv_b, xc, xcb);

    // 3. GEMM3: B_sel/C_sel via K-split MFMA partials + reduce; dt via f32 matvec
    gemm3_mfma<<<dim3(4, 4096 / 64), 256, 0, stream>>>(xcb, Wxt, P);
    gemm3_reduce<<<131072 / 256, 256, 0, stream>>>(P, b_x, scal);
    dt_matvec<<<4096 / 4, 256, 0, stream>>>(xc, W_x, b_x, scal);

    // 4. parallel log-space rates
    rates_par<<<NBATCH, 256, 0, stream>>>(scal, A_log, RP);

    // 5-7. chunked scan
    scan_states<<<dim3(DI / 128, NC, NBATCH), 128, 0, stream>>>(scal, xc, S);
    stitch<<<dim3(DI / 256, NBATCH), 256, 0, stream>>>(S, RP, Hin);
    scan_out<<<dim3(DI / 128, NC, NBATCH), 128, 0, stream>>>(scal, xc, Hin, Dw, xr, ybf);

    // 8. out = y_act @ W_out + b_out  (MFMA bf16: M=4096, N=512, K=1024)
    gemm_mfma<<<dim3(512 / 128, 4096 / 128), 256, 0, stream>>>(
        ybf, Wt2, b_out, out, 4096, 512, 1024);
}

// Round 5
// 139.273 us; speedup vs baseline: 10.8642x; 1.3853x over previous
//
#include <hip/hip_runtime.h>
#include <hip/hip_bf16.h>
#include <cmath>

// ---------------------------------------------------------------------------
// Mamba block: bf16-MFMA GEMMs + f32 dt matvec + fine-chunked scan (NC=64).
//   B=2, L=2048, D_MODEL=512, D_INNER=1024, D_STATE=16, D_CONV=4, EPS=1e-8
// Workspace layout (float units), ~71 MB (same budget as round 4):
//   xr   : 8,388,608   xc : 4,194,304   scal : 196,608
//   Sbf  : 2,097,152 ushort (=1,048,576 f)  per-chunk states, bf16,
//          stitched IN-PLACE (S[c] overwritten with corrected init state)
//   RP   : 2,048 f (per-chunk rate products, NC=64)
//   xbf  region: 1,048,576 f = x bf16; after GEMM1 reused as P + Wxt
//   Wt1  : 524,288 f   Wt2 : 262,144 f
//   ybf  region: 2,097,152 f = xcb (bf16 xc) then y_act bf16
// ---------------------------------------------------------------------------

#define L_SEQ 2048
#define NBATCH 2
#define DI 1024
#define NC 64
#define LC 32
#define EPS_F 1e-8f
#define LOG_EPS -18.420680744f

typedef __attribute__((ext_vector_type(8))) __bf16 bf16x8;
typedef __attribute__((ext_vector_type(4))) float f32x4;

__device__ __forceinline__ float silu_f(float v) {
    return v / (1.f + __expf(-v));
}

__device__ __forceinline__ ushort bf16_bits(float v) {
    __hip_bfloat16 h = __float2bfloat16(v);
    return *reinterpret_cast<ushort*>(&h);
}

__device__ __forceinline__ float bf2f(ushort u) {
    unsigned v = ((unsigned)u) << 16;
    union { unsigned u; float f; } c;
    c.u = v;
    return c.f;
}

// ---------------- bf16 MFMA GEMM: C[M,N] = A[M,K] @ Bt[N,K]^T + bias -------
__global__ __launch_bounds__(256) void gemm_mfma(
    const ushort* __restrict__ A, const ushort* __restrict__ Bt,
    const float* __restrict__ bias, float* __restrict__ C,
    int M, int N, int K)
{
    __shared__ ushort lA[128 * 64];
    __shared__ ushort lB[128 * 64];
    const int tid = threadIdx.x;
    const int w = tid >> 6, ln = tid & 63;
    const int wr = w >> 1, wc = w & 1;
    const int bm = blockIdx.y * 128, bn = blockIdx.x * 128;
    const int q = ln >> 4, r = ln & 15;
    f32x4 acc[4][4] = {};

    for (int k0 = 0; k0 < K; k0 += 64) {
        #pragma unroll
        for (int j = 0; j < 4; ++j) {
            int c = w * 4 + j;
            int i = c * 64 + ln;
            int m = i >> 3, k8 = (i & 7) * 8;
            __builtin_amdgcn_global_load_lds(
                (const __attribute__((address_space(1))) void*)(A + (size_t)(bm + m) * K + k0 + k8),
                (__attribute__((address_space(3))) void*)(lA + (size_t)i * 8),
                16, 0, 0);
            __builtin_amdgcn_global_load_lds(
                (const __attribute__((address_space(1))) void*)(Bt + (size_t)(bn + m) * K + k0 + k8),
                (__attribute__((address_space(3))) void*)(lB + (size_t)i * 8),
                16, 0, 0);
        }
        __syncthreads();
        #pragma unroll
        for (int kk = 0; kk < 2; ++kk) {
            const int ko = kk * 32 + q * 8;
            bf16x8 af[4], bfr[4];
            #pragma unroll
            for (int m = 0; m < 4; ++m)
                af[m] = *reinterpret_cast<const bf16x8*>(&lA[(wr * 64 + m * 16 + r) * 64 + ko]);
            #pragma unroll
            for (int n = 0; n < 4; ++n)
                bfr[n] = *reinterpret_cast<const bf16x8*>(&lB[(wc * 64 + n * 16 + r) * 64 + ko]);
            #pragma unroll
            for (int m = 0; m < 4; ++m)
                #pragma unroll
                for (int n = 0; n < 4; ++n)
                    acc[m][n] = __builtin_amdgcn_mfma_f32_16x16x32_bf16(af[m], bfr[n], acc[m][n], 0, 0, 0);
        }
        __syncthreads();
    }

    #pragma unroll
    for (int n = 0; n < 4; ++n) {
        int col = bn + wc * 64 + n * 16 + r;
        float bv = bias[col];
        #pragma unroll
        for (int m = 0; m < 4; ++m) {
            int row0 = bm + wr * 64 + m * 16 + q * 4;
            #pragma unroll
            for (int j = 0; j < 4; ++j)
                C[(size_t)(row0 + j) * N + col] = acc[m][n][j] + bv;
        }
    }
}

// ---------------- GEMM3 partials: P[ks][4096][32] = xcb @ Wxt^T ------------
__global__ __launch_bounds__(256) void gemm3_mfma(
    const ushort* __restrict__ A, const ushort* __restrict__ Bt,
    float* __restrict__ P)
{
    __shared__ ushort lA[64 * 64];
    __shared__ ushort lB[32 * 64];
    const int t = threadIdx.x;
    const int w = t >> 6, ln = t & 63;
    const int q = ln >> 4, r = ln & 15;
    const int bm = blockIdx.y * 64;
    const int ks = blockIdx.x;
    f32x4 a0 = {}, a1 = {};

    for (int k0 = ks * 256; k0 < ks * 256 + 256; k0 += 64) {
        #pragma unroll
        for (int jj = 0; jj < 2; ++jj) {
            int i = t + jj * 256;
            int m = i >> 3, k8 = (i & 7) * 8;
            __builtin_amdgcn_global_load_lds(
                (const __attribute__((address_space(1))) void*)(A + (size_t)(bm + m) * 1024 + k0 + k8),
                (__attribute__((address_space(3))) void*)(lA + (size_t)i * 8),
                16, 0, 0);
        }
        {
            int m = t >> 3, k8 = (t & 7) * 8;
            __builtin_amdgcn_global_load_lds(
                (const __attribute__((address_space(1))) void*)(Bt + (size_t)m * 1024 + k0 + k8),
                (__attribute__((address_space(3))) void*)(lB + (size_t)t * 8),
                16, 0, 0);
        }
        __syncthreads();
        #pragma unroll
        for (int kk = 0; kk < 2; ++kk) {
            const int ko = kk * 32 + q * 8;
            bf16x8 af = *reinterpret_cast<const bf16x8*>(&lA[(w * 16 + r) * 64 + ko]);
            bf16x8 b0 = *reinterpret_cast<const bf16x8*>(&lB[(r) * 64 + ko]);
            bf16x8 b1 = *reinterpret_cast<const bf16x8*>(&lB[(16 + r) * 64 + ko]);
            a0 = __builtin_amdgcn_mfma_f32_16x16x32_bf16(af, b0, a0, 0, 0, 0);
            a1 = __builtin_amdgcn_mfma_f32_16x16x32_bf16(af, b1, a1, 0, 0, 0);
        }
        __syncthreads();
    }

    const int row0 = bm + w * 16 + q * 4;
    const size_t base = (size_t)ks * 131072;
    #pragma unroll
    for (int j = 0; j < 4; ++j) {
        P[base + (size_t)(row0 + j) * 32 + r]      = a0[j];
        P[base + (size_t)(row0 + j) * 32 + 16 + r] = a1[j];
    }
}

// ---------------- GEMM3 reduce -------------------------------------------
__global__ __launch_bounds__(256) void gemm3_reduce(
    const float* __restrict__ P, const float* __restrict__ b_x,
    float* __restrict__ scal)
{
    int idx = blockIdx.x * 256 + threadIdx.x;
    int l = idx >> 5, c = idx & 31;
    float v = b_x[c] + P[idx] + P[idx + 131072] + P[idx + 262144] + P[idx + 393216];
    scal[(size_t)l * 48 + c] = v;
}

// ---------------- dt column (f32) ------------------------------------------
__global__ __launch_bounds__(256) void dt_matvec(
    const float* __restrict__ xc, const float* __restrict__ W_x,
    const float* __restrict__ b_x, float* __restrict__ scal)
{
    __shared__ float wcol[1024];
    const int t = threadIdx.x;
    #pragma unroll
    for (int i = 0; i < 4; ++i) wcol[t + i * 256] = W_x[(size_t)(t + i * 256) * 33 + 32];
    __syncthreads();
    const int wv = t >> 6, ln = t & 63;
    const size_t row = (size_t)blockIdx.x * 4 + wv;
    const float* xp = xc + row * 1024;
    float acc = 0.f;
    #pragma unroll
    for (int j = 0; j < 16; ++j) acc = fmaf(xp[ln + j * 64], wcol[ln + j * 64], acc);
    #pragma unroll
    for (int off = 32; off; off >>= 1) acc += __shfl_xor(acc, off, 64);
    if (ln == 0) scal[row * 48 + 32] = acc + b_x[32];
}

// ---------------- casts -----------------------------------------------------
__global__ __launch_bounds__(256) void cast_bf16(
    const float* __restrict__ src, ushort* __restrict__ dst, int n4)
{
    int i = blockIdx.x * 256 + threadIdx.x;
    if (i >= n4) return;
    float4 v = *reinterpret_cast<const float4*>(src + (size_t)i * 4);
    ushort4 o;
    o.x = bf16_bits(v.x); o.y = bf16_bits(v.y);
    o.z = bf16_bits(v.z); o.w = bf16_bits(v.w);
    *reinterpret_cast<ushort4*>(dst + (size_t)i * 4) = o;
}

__global__ __launch_bounds__(256) void tcast_bf16(
    const float* __restrict__ src, ushort* __restrict__ dst, int R, int Ccols)
{
    __shared__ float ld[64][65];
    int r0 = blockIdx.y * 64, c0 = blockIdx.x * 64;
    #pragma unroll
    for (int i = 0; i < 16; ++i) {
        int idx = threadIdx.x + i * 256;
        int rr = idx >> 6, cc = idx & 63;
        ld[rr][cc] = src[(size_t)(r0 + rr) * Ccols + c0 + cc];
    }
    __syncthreads();
    #pragma unroll
    for (int i = 0; i < 16; ++i) {
        int idx = threadIdx.x + i * 256;
        int cc = idx >> 6, rr = idx & 63;
        dst[(size_t)(c0 + cc) * R + r0 + rr] = bf16_bits(ld[rr][cc]);
    }
}

__global__ __launch_bounds__(256) void wxt_cast(
    const float* __restrict__ W_x, ushort* __restrict__ Wxt)
{
    int idx = blockIdx.x * 256 + threadIdx.x;
    int c = idx >> 10, k = idx & 1023;
    Wxt[idx] = bf16_bits(W_x[(size_t)k * 33 + c]);
}

// ---------------- depthwise causal conv(4) + SiLU --------------------------
__global__ __launch_bounds__(256) void conv_silu(
    const float* __restrict__ xr, const float* __restrict__ cw,
    const float* __restrict__ cb, float* __restrict__ xc,
    ushort* __restrict__ xcb)
{
    int idx = blockIdx.x * 256 + threadIdx.x;
    int d = idx & (DI - 1);
    int l = (idx >> 10) & (L_SEQ - 1);
    float4 w = *reinterpret_cast<const float4*>(cw + d * 4);
    float acc = cb[d];
    long base = ((long)(idx >> 10)) * 2048 + d;
    if (l >= 3) acc = fmaf(xr[base - 3 * 2048], w.x, acc);
    if (l >= 2) acc = fmaf(xr[base - 2 * 2048], w.y, acc);
    if (l >= 1) acc = fmaf(xr[base - 1 * 2048], w.z, acc);
    acc = fmaf(xr[base], w.w, acc);
    float v = silu_f(acc);
    xc[idx] = v;
    xcb[idx] = bf16_bits(v);
}

// ---------------- parallel rates via log-space scan (NC=64) ----------------
__global__ __launch_bounds__(256) void rates_par(
    float* __restrict__ scal, const float* __restrict__ A_log,
    float* __restrict__ RP)
{
    int b = blockIdx.x;
    int t = threadIdx.x;
    __shared__ float cdt[L_SEQ];
    __shared__ float wsum[4];
    __shared__ float An[16];
    if (t < 16) An[t] = -__expf(A_log[t]);
    float* base = scal + (long)b * L_SEQ * 48;

    float dt[8];
    float run = 0.f;
    const int l0 = t * 8;
    #pragma unroll
    for (int i = 0; i < 8; ++i) {
        float raw = base[(l0 + i) * 48 + 32];
        float d = (raw > 20.f) ? raw : log1pf(__expf(raw));
        dt[i] = d;
        run += d;
        cdt[l0 + i] = run;
    }

    float x = run;
    int lane = t & 63;
    #pragma unroll
    for (int d = 1; d < 64; d <<= 1) {
        float v = __shfl_up(x, d, 64);
        if (lane >= d) x += v;
    }
    int w = t >> 6;
    if (lane == 63) wsum[w] = x;
    __syncthreads();
    float woff = 0.f;
    for (int i = 0; i < w; ++i) woff += wsum[i];
    float toff = woff + x - run;
    #pragma unroll
    for (int i = 0; i < 8; ++i) cdt[l0 + i] += toff;
    __syncthreads();

    float cprev = (l0 == 0) ? 0.f : cdt[l0 - 1];
    #pragma unroll
    for (int i = 0; i < 8; ++i) {
        int l = l0 + i;
        float cl = cdt[l];
        float rv[16];
        #pragma unroll
        for (int s = 0; s < 16; ++s) {
            float A = An[s];
            float rr;
            if (A * cl >= LOG_EPS) {
                rr = __expf(A * dt[i]);
            } else {
                float lp = A * cprev;
                rr = (lp >= LOG_EPS) ? EPS_F / __expf(lp) : 1.f;
            }
            rv[s] = rr;
        }
        float4* dst = reinterpret_cast<float4*>(base + l * 48 + 32);
        dst[0] = *reinterpret_cast<float4*>(&rv[0]);
        dst[1] = *reinterpret_cast<float4*>(&rv[4]);
        dst[2] = *reinterpret_cast<float4*>(&rv[8]);
        dst[3] = *reinterpret_cast<float4*>(&rv[12]);
        cprev = cl;
    }

    // per-chunk products (chunk = 32 steps; thread 4c+3 owns chunk c)
    if ((t & 3) == 3) {
        int c = t >> 2;                    // 0..63
        float ce = cdt[c * LC + LC - 1];
        float cp = (c == 0) ? 0.f : cdt[c * LC - 1];
        for (int s = 0; s < 16; ++s) {
            float A = An[s];
            float pe = fmaxf(__expf(A * ce), EPS_F);
            float pp = fmaxf(__expf(A * cp), EPS_F);
            RP[(b * NC + c) * 16 + s] = pe / pp;
        }
    }
}

// ---------------- phase A: per-chunk local end states (bf16 out) -----------
__global__ __launch_bounds__(128) void scan_states(
    const float* __restrict__ scal, const float* __restrict__ xc,
    ushort* __restrict__ Sbf)
{
    int b = blockIdx.z, c = blockIdx.y;
    int d = blockIdx.x * 128 + threadIdx.x;
    __shared__ float sc[LC * 48];
    const float4* src = reinterpret_cast<const float4*>(scal + ((long)(b * L_SEQ) + c * LC) * 48);
    float4* dst = reinterpret_cast<float4*>(sc);
    for (int i = threadIdx.x; i < LC * 48 / 4; i += 128) dst[i] = src[i];
    __syncthreads();
    float h[16];
    #pragma unroll
    for (int s = 0; s < 16; ++s) h[s] = 0.f;
    const float* xcp = xc + ((long)(b * L_SEQ) + c * LC) * 1024 + d;
    float xn = xcp[0];
    for (int ll = 0; ll < LC; ++ll) {
        float xcv = xn;
        if (ll + 1 < LC) xn = xcp[(long)(ll + 1) * 1024];
        const float* e = sc + ll * 48;
        #pragma unroll
        for (int s = 0; s < 16; ++s) h[s] = fmaf(e[32 + s], h[s], e[s] * xcv);
    }
    ushort* Sp = Sbf + ((long)(b * NC + c) * 16) * 1024 + d;
    #pragma unroll
    for (int s = 0; s < 16; ++s) Sp[(long)s * 1024] = bf16_bits(h[s]);
}

// ---------------- stitch (in-place): S[c] -> corrected init state ----------
// thread = (b, s, d); serial over chunks. Reads local end state, replaces it
// with the corrected INITIAL state for that chunk.
__global__ __launch_bounds__(256) void stitch(
    ushort* __restrict__ Sbf, const float* __restrict__ RP)
{
    int idx = blockIdx.x * 256 + threadIdx.x;     // < 16384
    int b = blockIdx.y;
    int d = idx & 1023, s = idx >> 10;
    float H = 0.f;
    for (int c = 0; c < NC; ++c) {
        long off = ((long)((b * NC + c) * 16 + s)) * 1024 + d;
        float tmp = bf2f(Sbf[off]);
        Sbf[off] = bf16_bits(H);
        H = fmaf(RP[(b * NC + c) * 16 + s], H, tmp);
    }
}

// ---------------- phase B: full scan + y + gating -> bf16 ------------------
__global__ __launch_bounds__(128) void scan_out(
    const float* __restrict__ scal, const float* __restrict__ xc,
    const ushort* __restrict__ Hin, const float* __restrict__ Dw,
    const float* __restrict__ xr, ushort* __restrict__ ybf)
{
    int b = blockIdx.z, c = blockIdx.y;
    int d = blockIdx.x * 128 + threadIdx.x;
    __shared__ float sc[LC * 48];
    const float4* src = reinterpret_cast<const float4*>(scal + ((long)(b * L_SEQ) + c * LC) * 48);
    float4* dst = reinterpret_cast<float4*>(sc);
    for (int i = threadIdx.x; i < LC * 48 / 4; i += 128) dst[i] = src[i];
    __syncthreads();
    float h[16];
    long hoff = ((long)(b * NC + c) * 16) * 1024 + d;
    #pragma unroll
    for (int s = 0; s < 16; ++s) h[s] = bf2f(Hin[hoff + (long)s * 1024]);
    float Dd = Dw[d];
    const long row0 = (long)(b * L_SEQ) + c * LC;
    float xn = xc[row0 * 1024 + d];
    float rn = xr[row0 * 2048 + 1024 + d];
    for (int ll = 0; ll < LC; ++ll) {
        long row = row0 + ll;
        float xcv = xn, resv = rn;
        if (ll + 1 < LC) {
            xn = xc[(row + 1) * 1024 + d];
            rn = xr[(row + 1) * 2048 + 1024 + d];
        }
        const float* e = sc + ll * 48;
        float y = 0.f;
        #pragma unroll
        for (int s = 0; s < 16; ++s) {
            h[s] = fmaf(e[32 + s], h[s], e[s] * xcv);
            y = fmaf(e[16 + s], h[s], y);
        }
        y = fmaf(Dd, xcv, y);
        ybf[row * 1024 + d] = bf16_bits(y * silu_f(resv));
    }
}

// ---------------------------------------------------------------------------
extern "C" void kernel_launch(void* const* d_in, const int* in_sizes, int n_in,
                              void* d_out, int out_size, void* d_ws, size_t ws_size,
                              hipStream_t stream)
{
    const float* x      = (const float*)d_in[0];
    const float* W_in   = (const float*)d_in[1];
    const float* b_in   = (const float*)d_in[2];
    const float* conv_w = (const float*)d_in[3];
    const float* conv_b = (const float*)d_in[4];
    const float* W_x    = (const float*)d_in[5];
    const float* b_x    = (const float*)d_in[6];
    const float* A_log  = (const float*)d_in[7];
    const float* Dw     = (const float*)d_in[8];
    const float* W_out  = (const float*)d_in[9];
    const float* b_out  = (const float*)d_in[10];
    float* out = (float*)d_out;

    float* ws   = (float*)d_ws;
    float* xr   = ws;                           // 8,388,608 f
    float* xc   = xr + 8388608;                 // 4,194,304 f
    float* scal = xc + 4194304;                 //   196,608 f
    ushort* Sbf = (ushort*)(scal + 196608);     // 2,097,152 u (=1,048,576 f)
    float* RP   = (float*)(Sbf + 2097152);      //     2,048 f
    ushort* xbf = (ushort*)(RP + 2048);         // region 1,048,576 f
    float*  P   = (float*)xbf;                  //   alias: 524,288 f
    ushort* Wxt = (ushort*)(P + 524288);        //   alias: 32,768 u
    ushort* Wt1 = xbf + 2097152;                // 1,048,576 u
    ushort* Wt2 = Wt1 + 1048576;                //   524,288 u
    ushort* ybf = Wt2 + 524288;                 // 4,194,304 u
    ushort* xcb = ybf;                          //   alias (dead before scan_out)

    // 0. input casts
    cast_bf16<<<(4096 * 512 / 4 + 255) / 256, 256, 0, stream>>>(x, xbf, 4096 * 512 / 4);
    tcast_bf16<<<dim3(2048 / 64, 512 / 64), 256, 0, stream>>>(W_in, Wt1, 512, 2048);
    tcast_bf16<<<dim3(512 / 64, 1024 / 64), 256, 0, stream>>>(W_out, Wt2, 1024, 512);

    // 1. xr = x @ W_in + b_in  (MFMA bf16)
    gemm_mfma<<<dim3(2048 / 128, 4096 / 128), 256, 0, stream>>>(
        xbf, Wt1, b_in, xr, 4096, 2048, 512);

    // 1b. Wxt = W_x[:, 0:32]^T bf16 (xbf region reuse — after GEMM1)
    wxt_cast<<<32768 / 256, 256, 0, stream>>>(W_x, Wxt);

    // 2. xc = silu(conv(x_inner)) (f32 + bf16)
    conv_silu<<<(NBATCH * L_SEQ * DI) / 256, 256, 0, stream>>>(xr, conv_w, conv_b, xc, xcb);

    // 3. GEMM3: B/C via MFMA K-split, dt via f32 matvec
    gemm3_mfma<<<dim3(4, 4096 / 64), 256, 0, stream>>>(xcb, Wxt, P);
    gemm3_reduce<<<131072 / 256, 256, 0, stream>>>(P, b_x, scal);
    dt_matvec<<<4096 / 4, 256, 0, stream>>>(xc, W_x, b_x, scal);

    // 4. parallel log-space rates (NC=64 chunk products)
    rates_par<<<NBATCH, 256, 0, stream>>>(scal, A_log, RP);

    // 5-7. fine-chunked scan (1024-block phases, in-place stitch)
    scan_states<<<dim3(DI / 128, NC, NBATCH), 128, 0, stream>>>(scal, xc, Sbf);
    stitch<<<dim3(64, NBATCH), 256, 0, stream>>>(Sbf, RP);
    scan_out<<<dim3(DI / 128, NC, NBATCH), 128, 0, stream>>>(scal, xc, Sbf, Dw, xr, ybf);

    // 8. out = y_act @ W_out + b_out  (MFMA bf16)
    gemm_mfma<<<dim3(512 / 128, 4096 / 128), 256, 0, stream>>>(
        ybf, Wt2, b_out, out, 4096, 512, 1024);
}

// Round 6
// 135.415 us; speedup vs baseline: 11.1737x; 1.0285x over previous
//
#include <hip/hip_runtime.h>
#include <hip/hip_bf16.h>
#include <cmath>

// ---------------------------------------------------------------------------
// Mamba block: bf16-MFMA GEMMs + f32 dt matvec + fine-chunked scan (NC=64),
// latency-flattened stitch/scan (batched register loads), split GEMM1 output.
//   B=2, L=2048, D_MODEL=512, D_INNER=1024, D_STATE=16, D_CONV=4, EPS=1e-8
// Workspace (float units), ~63 MB:
//   xin  : (B,L,1024) f32 = 4,194,304   GEMM1 cols [0:1024)
//   resb : (B,L,1024) bf16= 2,097,152 f GEMM1 cols [1024:2048) (gate only)
//   xc   : 4,194,304   scal : 196,608
//   Sbf  : 2,097,152 u (=1,048,576 f)   chunk states, stitched in-place
//   RP   : 2,048 f
//   xbf  region: 1,048,576 f = x bf16; after GEMM1 reused as P + Wxt
//   Wt1  : 524,288 f   Wt2 : 262,144 f
//   ybf  region: 2,097,152 f = xcb (bf16 xc) then y_act bf16
// ---------------------------------------------------------------------------

#define L_SEQ 2048
#define NBATCH 2
#define DI 1024
#define NC 64
#define LC 32
#define EPS_F 1e-8f
#define LOG_EPS -18.420680744f

typedef __attribute__((ext_vector_type(8))) __bf16 bf16x8;
typedef __attribute__((ext_vector_type(4))) float f32x4;

__device__ __forceinline__ float silu_f(float v) {
    return v / (1.f + __expf(-v));
}

__device__ __forceinline__ ushort bf16_bits(float v) {
    __hip_bfloat16 h = __float2bfloat16(v);
    return *reinterpret_cast<ushort*>(&h);
}

__device__ __forceinline__ float bf2f(ushort u) {
    union { unsigned u; float f; } c;
    c.u = ((unsigned)u) << 16;
    return c.f;
}

// ---------------- bf16 MFMA GEMM: C = A @ Bt^T + bias ----------------------
// Columns [0, nsplit) -> f32 into Cf (ld nsplit);
// columns [nsplit, N) -> bf16 into Cb (ld N-nsplit). bn is tile-uniform.
__global__ __launch_bounds__(256) void gemm_mfma(
    const ushort* __restrict__ A, const ushort* __restrict__ Bt,
    const float* __restrict__ bias, float* __restrict__ Cf,
    ushort* __restrict__ Cb, int M, int N, int K, int nsplit)
{
    __shared__ ushort lA[128 * 64];
    __shared__ ushort lB[128 * 64];
    const int tid = threadIdx.x;
    const int w = tid >> 6, ln = tid & 63;
    const int wr = w >> 1, wc = w & 1;
    const int bm = blockIdx.y * 128, bn = blockIdx.x * 128;
    const int q = ln >> 4, r = ln & 15;
    f32x4 acc[4][4] = {};

    for (int k0 = 0; k0 < K; k0 += 64) {
        #pragma unroll
        for (int j = 0; j < 4; ++j) {
            int c = w * 4 + j;
            int i = c * 64 + ln;
            int m = i >> 3, k8 = (i & 7) * 8;
            __builtin_amdgcn_global_load_lds(
                (const __attribute__((address_space(1))) void*)(A + (size_t)(bm + m) * K + k0 + k8),
                (__attribute__((address_space(3))) void*)(lA + (size_t)i * 8),
                16, 0, 0);
            __builtin_amdgcn_global_load_lds(
                (const __attribute__((address_space(1))) void*)(Bt + (size_t)(bn + m) * K + k0 + k8),
                (__attribute__((address_space(3))) void*)(lB + (size_t)i * 8),
                16, 0, 0);
        }
        __syncthreads();
        #pragma unroll
        for (int kk = 0; kk < 2; ++kk) {
            const int ko = kk * 32 + q * 8;
            bf16x8 af[4], bfr[4];
            #pragma unroll
            for (int m = 0; m < 4; ++m)
                af[m] = *reinterpret_cast<const bf16x8*>(&lA[(wr * 64 + m * 16 + r) * 64 + ko]);
            #pragma unroll
            for (int n = 0; n < 4; ++n)
                bfr[n] = *reinterpret_cast<const bf16x8*>(&lB[(wc * 64 + n * 16 + r) * 64 + ko]);
            #pragma unroll
            for (int m = 0; m < 4; ++m)
                #pragma unroll
                for (int n = 0; n < 4; ++n)
                    acc[m][n] = __builtin_amdgcn_mfma_f32_16x16x32_bf16(af[m], bfr[n], acc[m][n], 0, 0, 0);
        }
        __syncthreads();
    }

    const bool f32path = (bn < nsplit);
    #pragma unroll
    for (int n = 0; n < 4; ++n) {
        int col = bn + wc * 64 + n * 16 + r;
        float bv = bias[col];
        #pragma unroll
        for (int m = 0; m < 4; ++m) {
            int row0 = bm + wr * 64 + m * 16 + q * 4;
            #pragma unroll
            for (int j = 0; j < 4; ++j) {
                float v = acc[m][n][j] + bv;
                if (f32path)
                    Cf[(size_t)(row0 + j) * nsplit + col] = v;
                else
                    Cb[(size_t)(row0 + j) * (N - nsplit) + (col - nsplit)] = bf16_bits(v);
            }
        }
    }
}

// ---------------- GEMM3 partials: P[ks][4096][32] = xcb @ Wxt^T ------------
__global__ __launch_bounds__(256) void gemm3_mfma(
    const ushort* __restrict__ A, const ushort* __restrict__ Bt,
    float* __restrict__ P)
{
    __shared__ ushort lA[64 * 64];
    __shared__ ushort lB[32 * 64];
    const int t = threadIdx.x;
    const int w = t >> 6, ln = t & 63;
    const int q = ln >> 4, r = ln & 15;
    const int bm = blockIdx.y * 64;
    const int ks = blockIdx.x;
    f32x4 a0 = {}, a1 = {};

    for (int k0 = ks * 256; k0 < ks * 256 + 256; k0 += 64) {
        #pragma unroll
        for (int jj = 0; jj < 2; ++jj) {
            int i = t + jj * 256;
            int m = i >> 3, k8 = (i & 7) * 8;
            __builtin_amdgcn_global_load_lds(
                (const __attribute__((address_space(1))) void*)(A + (size_t)(bm + m) * 1024 + k0 + k8),
                (__attribute__((address_space(3))) void*)(lA + (size_t)i * 8),
                16, 0, 0);
        }
        {
            int m = t >> 3, k8 = (t & 7) * 8;
            __builtin_amdgcn_global_load_lds(
                (const __attribute__((address_space(1))) void*)(Bt + (size_t)m * 1024 + k0 + k8),
                (__attribute__((address_space(3))) void*)(lB + (size_t)t * 8),
                16, 0, 0);
        }
        __syncthreads();
        #pragma unroll
        for (int kk = 0; kk < 2; ++kk) {
            const int ko = kk * 32 + q * 8;
            bf16x8 af = *reinterpret_cast<const bf16x8*>(&lA[(w * 16 + r) * 64 + ko]);
            bf16x8 b0 = *reinterpret_cast<const bf16x8*>(&lB[(r) * 64 + ko]);
            bf16x8 b1 = *reinterpret_cast<const bf16x8*>(&lB[(16 + r) * 64 + ko]);
            a0 = __builtin_amdgcn_mfma_f32_16x16x32_bf16(af, b0, a0, 0, 0, 0);
            a1 = __builtin_amdgcn_mfma_f32_16x16x32_bf16(af, b1, a1, 0, 0, 0);
        }
        __syncthreads();
    }

    const int row0 = bm + w * 16 + q * 4;
    const size_t base = (size_t)ks * 131072;
    #pragma unroll
    for (int j = 0; j < 4; ++j) {
        P[base + (size_t)(row0 + j) * 32 + r]      = a0[j];
        P[base + (size_t)(row0 + j) * 32 + 16 + r] = a1[j];
    }
}

// ---------------- GEMM3 reduce ---------------------------------------------
__global__ __launch_bounds__(256) void gemm3_reduce(
    const float* __restrict__ P, const float* __restrict__ b_x,
    float* __restrict__ scal)
{
    int idx = blockIdx.x * 256 + threadIdx.x;
    int l = idx >> 5, c = idx & 31;
    float v = b_x[c] + P[idx] + P[idx + 131072] + P[idx + 262144] + P[idx + 393216];
    scal[(size_t)l * 48 + c] = v;
}

// ---------------- dt column (f32) ------------------------------------------
__global__ __launch_bounds__(256) void dt_matvec(
    const float* __restrict__ xc, const float* __restrict__ W_x,
    const float* __restrict__ b_x, float* __restrict__ scal)
{
    __shared__ float wcol[1024];
    const int t = threadIdx.x;
    #pragma unroll
    for (int i = 0; i < 4; ++i) wcol[t + i * 256] = W_x[(size_t)(t + i * 256) * 33 + 32];
    __syncthreads();
    const int wv = t >> 6, ln = t & 63;
    const size_t row = (size_t)blockIdx.x * 4 + wv;
    const float* xp = xc + row * 1024;
    float acc = 0.f;
    #pragma unroll
    for (int j = 0; j < 16; ++j) acc = fmaf(xp[ln + j * 64], wcol[ln + j * 64], acc);
    #pragma unroll
    for (int off = 32; off; off >>= 1) acc += __shfl_xor(acc, off, 64);
    if (ln == 0) scal[row * 48 + 32] = acc + b_x[32];
}

// ---------------- casts -----------------------------------------------------
__global__ __launch_bounds__(256) void cast_bf16(
    const float* __restrict__ src, ushort* __restrict__ dst, int n4)
{
    int i = blockIdx.x * 256 + threadIdx.x;
    if (i >= n4) return;
    float4 v = *reinterpret_cast<const float4*>(src + (size_t)i * 4);
    ushort4 o;
    o.x = bf16_bits(v.x); o.y = bf16_bits(v.y);
    o.z = bf16_bits(v.z); o.w = bf16_bits(v.w);
    *reinterpret_cast<ushort4*>(dst + (size_t)i * 4) = o;
}

__global__ __launch_bounds__(256) void tcast_bf16(
    const float* __restrict__ src, ushort* __restrict__ dst, int R, int Ccols)
{
    __shared__ float ld[64][65];
    int r0 = blockIdx.y * 64, c0 = blockIdx.x * 64;
    #pragma unroll
    for (int i = 0; i < 16; ++i) {
        int idx = threadIdx.x + i * 256;
        int rr = idx >> 6, cc = idx & 63;
        ld[rr][cc] = src[(size_t)(r0 + rr) * Ccols + c0 + cc];
    }
    __syncthreads();
    #pragma unroll
    for (int i = 0; i < 16; ++i) {
        int idx = threadIdx.x + i * 256;
        int cc = idx >> 6, rr = idx & 63;
        dst[(size_t)(c0 + cc) * R + r0 + rr] = bf16_bits(ld[rr][cc]);
    }
}

__global__ __launch_bounds__(256) void wxt_cast(
    const float* __restrict__ W_x, ushort* __restrict__ Wxt)
{
    int idx = blockIdx.x * 256 + threadIdx.x;
    int c = idx >> 10, k = idx & 1023;
    Wxt[idx] = bf16_bits(W_x[(size_t)k * 33 + c]);
}

// ---------------- depthwise causal conv(4) + SiLU (contiguous xin) ---------
__global__ __launch_bounds__(256) void conv_silu(
    const float* __restrict__ xin, const float* __restrict__ cw,
    const float* __restrict__ cb, float* __restrict__ xc,
    ushort* __restrict__ xcb)
{
    int idx = blockIdx.x * 256 + threadIdx.x;
    int d = idx & (DI - 1);
    int l = (idx >> 10) & (L_SEQ - 1);
    float4 w = *reinterpret_cast<const float4*>(cw + d * 4);
    float acc = cb[d];
    long base = (long)idx;                        // (b*L + l)*1024 + d
    if (l >= 3) acc = fmaf(xin[base - 3 * 1024], w.x, acc);
    if (l >= 2) acc = fmaf(xin[base - 2 * 1024], w.y, acc);
    if (l >= 1) acc = fmaf(xin[base - 1 * 1024], w.z, acc);
    acc = fmaf(xin[base], w.w, acc);
    float v = silu_f(acc);
    xc[idx] = v;
    xcb[idx] = bf16_bits(v);
}

// ---------------- parallel rates via log-space scan (NC=64) ----------------
__global__ __launch_bounds__(256) void rates_par(
    float* __restrict__ scal, const float* __restrict__ A_log,
    float* __restrict__ RP)
{
    int b = blockIdx.x;
    int t = threadIdx.x;
    __shared__ float cdt[L_SEQ];
    __shared__ float wsum[4];
    __shared__ float An[16];
    if (t < 16) An[t] = -__expf(A_log[t]);
    float* base = scal + (long)b * L_SEQ * 48;

    float dt[8];
    float run = 0.f;
    const int l0 = t * 8;
    #pragma unroll
    for (int i = 0; i < 8; ++i) {
        float raw = base[(l0 + i) * 48 + 32];
        float d = (raw > 20.f) ? raw : log1pf(__expf(raw));
        dt[i] = d;
        run += d;
        cdt[l0 + i] = run;
    }

    float x = run;
    int lane = t & 63;
    #pragma unroll
    for (int d = 1; d < 64; d <<= 1) {
        float v = __shfl_up(x, d, 64);
        if (lane >= d) x += v;
    }
    int w = t >> 6;
    if (lane == 63) wsum[w] = x;
    __syncthreads();
    float woff = 0.f;
    for (int i = 0; i < w; ++i) woff += wsum[i];
    float toff = woff + x - run;
    #pragma unroll
    for (int i = 0; i < 8; ++i) cdt[l0 + i] += toff;
    __syncthreads();

    float cprev = (l0 == 0) ? 0.f : cdt[l0 - 1];
    #pragma unroll
    for (int i = 0; i < 8; ++i) {
        int l = l0 + i;
        float cl = cdt[l];
        float rv[16];
        #pragma unroll
        for (int s = 0; s < 16; ++s) {
            float A = An[s];
            float rr;
            if (A * cl >= LOG_EPS) {
                rr = __expf(A * dt[i]);
            } else {
                float lp = A * cprev;
                rr = (lp >= LOG_EPS) ? EPS_F / __expf(lp) : 1.f;
            }
            rv[s] = rr;
        }
        float4* dst = reinterpret_cast<float4*>(base + l * 48 + 32);
        dst[0] = *reinterpret_cast<float4*>(&rv[0]);
        dst[1] = *reinterpret_cast<float4*>(&rv[4]);
        dst[2] = *reinterpret_cast<float4*>(&rv[8]);
        dst[3] = *reinterpret_cast<float4*>(&rv[12]);
        cprev = cl;
    }

    if ((t & 3) == 3) {
        int c = t >> 2;
        float ce = cdt[c * LC + LC - 1];
        float cp = (c == 0) ? 0.f : cdt[c * LC - 1];
        for (int s = 0; s < 16; ++s) {
            float A = An[s];
            float pe = fmaxf(__expf(A * ce), EPS_F);
            float pp = fmaxf(__expf(A * cp), EPS_F);
            RP[(b * NC + c) * 16 + s] = pe / pp;
        }
    }
}

// ---------------- phase A: per-chunk local end states (bf16 out) -----------
__global__ __launch_bounds__(128) void scan_states(
    const float* __restrict__ scal, const float* __restrict__ xc,
    ushort* __restrict__ Sbf)
{
    int b = blockIdx.z, c = blockIdx.y;
    int d = blockIdx.x * 128 + threadIdx.x;
    __shared__ float sc[LC * 48];
    const float4* src = reinterpret_cast<const float4*>(scal + ((long)(b * L_SEQ) + c * LC) * 48);
    float4* dst = reinterpret_cast<float4*>(sc);
    for (int i = threadIdx.x; i < LC * 48 / 4; i += 128) dst[i] = src[i];

    // batch all xc loads for the chunk (independent; overlap the LDS staging)
    const float* xcp = xc + ((long)(b * L_SEQ) + c * LC) * 1024 + d;
    float xv[LC];
    #pragma unroll
    for (int ll = 0; ll < LC; ++ll) xv[ll] = xcp[(long)ll * 1024];
    __syncthreads();

    float h[16];
    #pragma unroll
    for (int s = 0; s < 16; ++s) h[s] = 0.f;
    #pragma unroll
    for (int ll = 0; ll < LC; ++ll) {
        const float* e = sc + ll * 48;
        #pragma unroll
        for (int s = 0; s < 16; ++s) h[s] = fmaf(e[32 + s], h[s], e[s] * xv[ll]);
    }
    ushort* Sp = Sbf + ((long)(b * NC + c) * 16) * 1024 + d;
    #pragma unroll
    for (int s = 0; s < 16; ++s) Sp[(long)s * 1024] = bf16_bits(h[s]);
}

// ---------------- stitch (in-place, batched): S[c] -> corrected init -------
__global__ __launch_bounds__(256) void stitch(
    ushort* __restrict__ Sbf, const float* __restrict__ RP)
{
    const int tid = threadIdx.x;
    const int idx = blockIdx.x * 256 + tid;       // < 16384
    const int b = blockIdx.y;
    const int d = idx & 1023, s = idx >> 10;      // s uniform per block
    __shared__ float rps[NC];
    if (tid < NC) rps[tid] = RP[(b * NC + tid) * 16 + s];

    const long base = ((long)(b * NC) * 16 + s) * 1024 + d;
    const long cs = 16 * 1024;
    float v[NC];
    #pragma unroll
    for (int c = 0; c < NC; ++c) v[c] = bf2f(Sbf[base + c * cs]);   // gather
    __syncthreads();
    float H = 0.f;
    #pragma unroll
    for (int c = 0; c < NC; ++c) {                                   // chain
        float tmp = v[c];
        v[c] = H;
        H = fmaf(rps[c], H, tmp);
    }
    #pragma unroll
    for (int c = 0; c < NC; ++c) Sbf[base + c * cs] = bf16_bits(v[c]); // scatter
}

// ---------------- phase B: full scan + y + gating -> bf16 ------------------
__global__ __launch_bounds__(128) void scan_out(
    const float* __restrict__ scal, const float* __restrict__ xc,
    const ushort* __restrict__ Hin, const float* __restrict__ Dw,
    const ushort* __restrict__ resb, ushort* __restrict__ ybf)
{
    int b = blockIdx.z, c = blockIdx.y;
    int d = blockIdx.x * 128 + threadIdx.x;
    __shared__ float sc[LC * 48];
    const float4* src = reinterpret_cast<const float4*>(scal + ((long)(b * L_SEQ) + c * LC) * 48);
    float4* dst = reinterpret_cast<float4*>(sc);
    for (int i = threadIdx.x; i < LC * 48 / 4; i += 128) dst[i] = src[i];

    const long row0 = (long)(b * L_SEQ) + c * LC;
    // batch-load chunk inputs (independent loads, overlap LDS staging)
    float xv[LC], rv[LC];
    #pragma unroll
    for (int ll = 0; ll < LC; ++ll) xv[ll] = xc[(row0 + ll) * 1024 + d];
    #pragma unroll
    for (int ll = 0; ll < LC; ++ll) rv[ll] = bf2f(resb[(row0 + ll) * 1024 + d]);
    float h[16];
    long hoff = ((long)(b * NC + c) * 16) * 1024 + d;
    #pragma unroll
    for (int s = 0; s < 16; ++s) h[s] = bf2f(Hin[hoff + (long)s * 1024]);
    __syncthreads();

    float Dd = Dw[d];
    #pragma unroll
    for (int ll = 0; ll < LC; ++ll) {
        const float* e = sc + ll * 48;
        float y = 0.f;
        #pragma unroll
        for (int s = 0; s < 16; ++s) {
            h[s] = fmaf(e[32 + s], h[s], e[s] * xv[ll]);
            y = fmaf(e[16 + s], h[s], y);
        }
        y = fmaf(Dd, xv[ll], y);
        ybf[(row0 + ll) * 1024 + d] = bf16_bits(y * silu_f(rv[ll]));
    }
}

// ---------------------------------------------------------------------------
extern "C" void kernel_launch(void* const* d_in, const int* in_sizes, int n_in,
                              void* d_out, int out_size, void* d_ws, size_t ws_size,
                              hipStream_t stream)
{
    const float* x      = (const float*)d_in[0];
    const float* W_in   = (const float*)d_in[1];
    const float* b_in   = (const float*)d_in[2];
    const float* conv_w = (const float*)d_in[3];
    const float* conv_b = (const float*)d_in[4];
    const float* W_x    = (const float*)d_in[5];
    const float* b_x    = (const float*)d_in[6];
    const float* A_log  = (const float*)d_in[7];
    const float* Dw     = (const float*)d_in[8];
    const float* W_out  = (const float*)d_in[9];
    const float* b_out  = (const float*)d_in[10];
    float* out = (float*)d_out;

    float* ws    = (float*)d_ws;
    float* xin   = ws;                          // 4,194,304 f
    ushort* resb = (ushort*)(xin + 4194304);    // 4,194,304 u (2,097,152 f)
    float* xc    = (float*)(resb + 4194304);    // 4,194,304 f
    float* scal  = xc + 4194304;                //   196,608 f
    ushort* Sbf  = (ushort*)(scal + 196608);    // 2,097,152 u
    float* RP    = (float*)(Sbf + 2097152);     //     2,048 f
    ushort* xbf  = (ushort*)(RP + 2048);        // region 1,048,576 f
    float*  P    = (float*)xbf;                 //   alias: 524,288 f
    ushort* Wxt  = (ushort*)(P + 524288);       //   alias: 32,768 u
    ushort* Wt1  = xbf + 2097152;               // 1,048,576 u
    ushort* Wt2  = Wt1 + 1048576;               //   524,288 u
    ushort* ybf  = Wt2 + 524288;                // 4,194,304 u
    ushort* xcb  = ybf;                         //   alias (dead before scan_out)

    // 0. input casts
    cast_bf16<<<(4096 * 512 / 4 + 255) / 256, 256, 0, stream>>>(x, xbf, 4096 * 512 / 4);
    tcast_bf16<<<dim3(2048 / 64, 512 / 64), 256, 0, stream>>>(W_in, Wt1, 512, 2048);
    tcast_bf16<<<dim3(512 / 64, 1024 / 64), 256, 0, stream>>>(W_out, Wt2, 1024, 512);

    // 1. [xin | resb] = x @ W_in + b_in  (split epilogue: f32 | bf16)
    gemm_mfma<<<dim3(2048 / 128, 4096 / 128), 256, 0, stream>>>(
        xbf, Wt1, b_in, xin, resb, 4096, 2048, 512, 1024);

    // 1b. Wxt = W_x[:, 0:32]^T bf16 (xbf region reuse — after GEMM1)
    wxt_cast<<<32768 / 256, 256, 0, stream>>>(W_x, Wxt);

    // 2. xc = silu(conv(xin)) (f32 + bf16)
    conv_silu<<<(NBATCH * L_SEQ * DI) / 256, 256, 0, stream>>>(xin, conv_w, conv_b, xc, xcb);

    // 3. GEMM3: B/C via MFMA K-split, dt via f32 matvec
    gemm3_mfma<<<dim3(4, 4096 / 64), 256, 0, stream>>>(xcb, Wxt, P);
    gemm3_reduce<<<131072 / 256, 256, 0, stream>>>(P, b_x, scal);
    dt_matvec<<<4096 / 4, 256, 0, stream>>>(xc, W_x, b_x, scal);

    // 4. parallel log-space rates
    rates_par<<<NBATCH, 256, 0, stream>>>(scal, A_log, RP);

    // 5-7. fine-chunked scan, latency-flattened
    scan_states<<<dim3(DI / 128, NC, NBATCH), 128, 0, stream>>>(scal, xc, Sbf);
    stitch<<<dim3(64, NBATCH), 256, 0, stream>>>(Sbf, RP);
    scan_out<<<dim3(DI / 128, NC, NBATCH), 128, 0, stream>>>(scal, xc, Sbf, Dw, resb, ybf);

    // 8. out = y_act @ W_out + b_out  (all-f32 epilogue: nsplit = N)
    gemm_mfma<<<dim3(512 / 128, 4096 / 128), 256, 0, stream>>>(
        ybf, Wt2, b_out, out, nullptr, 4096, 512, 1024, 512);
}